// Round 5
// baseline (2742.733 us; speedup 1.0000x reference)
//
#include <hip/hip_runtime.h>
#include <hip/hip_fp16.h>

#define D 128
#define SC 8            // src chunks (spmm L2 locality)
#define NDC 8           // node-hist dst chunks
#define NSLN 32         // node-hist edge slices
#define NSLB 128        // (B,sc)-hist edge slices
#define PBNMAX 6336     // packed node-hist counters per chunk (12672 bins max)
#define BINSMAX 12672   // (B,sc) bins max

typedef _Float16 half8 __attribute__((ext_vector_type(8)));
typedef float f32x4 __attribute__((ext_vector_type(4)));

__device__ inline uint pack_f16x2(float a, float b) {
  __half2 h = __floats2half2_rn(a, b);
  return *reinterpret_cast<uint*>(&h);
}
__device__ inline float2 unpack_f16x2(uint p) {
  __half2 h = *reinterpret_cast<__half2*>(&p);
  return __half22float2(h);
}
__device__ inline uint mdiv40(uint x, uint M) {  // x / d with M = ceil(2^40/d)
  return (uint)(((unsigned long long)x * M) >> 40);
}

// ---------------- node histogram (counts only, for ns/nd) ----------------

__global__ __launch_bounds__(1024) void k_histnode(const int* __restrict__ esrc,
                                                   const int* __restrict__ edst,
                                                   uint* __restrict__ pdN,
                                                   uint* __restrict__ psN,
                                                   int E, int N, int DB, int S) {
  __shared__ uint hd[PBNMAX];
  __shared__ uint hs_[PBNMAX];
  const int t = threadIdx.x;
  const int sl = blockIdx.x / NDC;   // consecutive blocks share a slice (L2 reuse)
  const int dc = blockIdx.x % NDC;
  const int PBN = DB >> 1;
  for (int j = t; j < PBN; j += 1024) { hd[j] = 0u; hs_[j] = 0u; }
  __syncthreads();
  const int c0 = dc * DB;
  const int c1 = min(c0 + DB, N);
  const int i0 = sl * S;             // S multiple of 4
  const int i1 = min(i0 + S, E);
  for (int vi = (i0 >> 2) + t; vi < ((i1 + 3) >> 2); vi += 1024) {
    const int ib = vi << 2;
    int dv[4], sv[4];
    if (ib + 3 < i1) {
      const int4 d4 = reinterpret_cast<const int4*>(edst)[vi];
      const int4 s4 = reinterpret_cast<const int4*>(esrc)[vi];
      dv[0] = d4.x; dv[1] = d4.y; dv[2] = d4.z; dv[3] = d4.w;
      sv[0] = s4.x; sv[1] = s4.y; sv[2] = s4.z; sv[3] = s4.w;
    } else {
#pragma unroll
      for (int k = 0; k < 4; ++k) {
        dv[k] = (ib + k < i1) ? edst[ib + k] : -1;
        sv[k] = (ib + k < i1) ? esrc[ib + k] : -1;
      }
    }
#pragma unroll
    for (int k = 0; k < 4; ++k) {
      const int d = dv[k];
      if (d >= c0 && d < c1) {
        const uint bl = (uint)(d - c0);
        atomicAdd(&hd[bl >> 1], 1u << (16u * (bl & 1u)));
      }
      const int s = sv[k];
      if (s >= c0 && s < c1) {
        const uint bl = (uint)(s - c0);
        atomicAdd(&hs_[bl >> 1], 1u << (16u * (bl & 1u)));
      }
    }
  }
  __syncthreads();
  uint* pd = pdN + (size_t)blockIdx.x * PBN;
  uint* ps = psN + (size_t)blockIdx.x * PBN;
  for (int j = t; j < PBN; j += 1024) { pd[j] = hd[j]; ps[j] = hs_[j]; }
}

__global__ void k_reduceN(const uint* __restrict__ pdN, const uint* __restrict__ psN,
                          float* __restrict__ ns, float* __restrict__ nd,
                          int N, int DB) {
  const int j = blockIdx.x * 256 + threadIdx.x;  // packed pair index
  const int n0 = j * 2;
  if (n0 >= N) return;
  const int dc = n0 / DB;
  const int jj = (n0 - dc * DB) >> 1;
  const int PBN = DB >> 1;
  uint dlo = 0, dhi = 0, slo = 0, shi = 0;
  for (int sl = 0; sl < NSLN; ++sl) {
    const uint v = pdN[(size_t)(sl * NDC + dc) * PBN + jj];
    dlo += v & 0xffffu; dhi += v >> 16;
    const uint w = psN[(size_t)(sl * NDC + dc) * PBN + jj];
    slo += w & 0xffffu; shi += w >> 16;
  }
  nd[n0] = rsqrtf((float)max(dlo, 1u));
  ns[n0] = rsqrtf((float)max(slo, 1u));
  if (n0 + 1 < N) {
    nd[n0 + 1] = rsqrtf((float)max(dhi, 1u));
    ns[n0 + 1] = rsqrtf((float)max(shi, 1u));
  }
}

// ---------------- (dst-block, src-chunk) histogram with rank record ----------------

__global__ __launch_bounds__(1024) void k_histB(const int* __restrict__ esrc,
                                                const int* __restrict__ edst,
                                                ushort* __restrict__ pB,
                                                uchar* __restrict__ rank8,
                                                int E, int BINS, uint Mcsz, int SB) {
  __shared__ uint hB[BINSMAX];
  const int t = threadIdx.x;
  const int sl = blockIdx.x;
  for (int j = t; j < BINS; j += 1024) hB[j] = 0u;
  __syncthreads();
  const int i0 = sl * SB;
  const int i1 = min(i0 + SB, E);
  for (int i = i0 + t; i < i1; i += 1024) {
    const int d = edst[i];
    const uint sc = mdiv40((uint)esrc[i], Mcsz);
    const int bin = (d >> 6) * SC + (int)sc;
    const uint old = atomicAdd(&hB[bin], 1u);
    rank8[i] = (uchar)old;
  }
  __syncthreads();
  ushort* p = pB + (size_t)sl * BINS;
  for (int j = t; j < BINS; j += 1024) p[j] = (ushort)hB[j];
}

// in-place exclusive slice-prefix per bin; bin totals out
__global__ void k_reduceB(ushort* __restrict__ pB, int* __restrict__ btot, int BINS) {
  const int bin = blockIdx.x * 256 + threadIdx.x;
  if (bin >= BINS) return;
  uint run = 0;
  for (int sl = 0; sl < NSLB; ++sl) {
    ushort* p = pB + (size_t)sl * BINS + bin;
    const uint v = *p;
    *p = (ushort)run;
    run += v;
  }
  btot[bin] = (int)run;
}

// ---------------- scan over btot -> bofs ----------------

__global__ __launch_bounds__(256) void k_scan_partial(const int* __restrict__ tot,
                                                      int* __restrict__ csum, int n) {
  __shared__ int sd[256];
  const int b = blockIdx.x, t = threadIdx.x;
  const int base = b * 1024 + t * 4;
  int s = 0;
#pragma unroll
  for (int i = 0; i < 4; ++i) { int idx = base + i; if (idx < n) s += tot[idx]; }
  sd[t] = s; __syncthreads();
  for (int off = 128; off > 0; off >>= 1) {
    if (t < off) sd[t] += sd[t + off];
    __syncthreads();
  }
  if (t == 0) csum[b] = sd[0];
}

__global__ void k_scan_serial(int* __restrict__ csum, int nch,
                              int* __restrict__ ofs, int n) {
  if (blockIdx.x == 0 && threadIdx.x == 0) {
    int run = 0;
    for (int b = 0; b < nch; ++b) { int v = csum[b]; csum[b] = run; run += v; }
    ofs[n] = run;
  }
}

__global__ __launch_bounds__(256) void k_scan_final(const int* __restrict__ tot,
                                                    const int* __restrict__ csum,
                                                    int* __restrict__ ofs, int n) {
  __shared__ int sd[256];
  const int b = blockIdx.x, t = threadIdx.x;
  const int base = b * 1024 + t * 4;
  int v[4]; int s = 0;
#pragma unroll
  for (int i = 0; i < 4; ++i) { v[i] = (base + i < n) ? tot[base + i] : 0; s += v[i]; }
  sd[t] = s; __syncthreads();
  for (int off = 1; off < 256; off <<= 1) {
    int x = (t >= off) ? sd[t - off] : 0;
    __syncthreads();
    sd[t] += x;
    __syncthreads();
  }
  int o = sd[t] - s + csum[b];
#pragma unroll
  for (int i = 0; i < 4; ++i) {
    if (base + i < n) { ofs[base + i] = o; o += v[i]; }
  }
}

// ---------------- atomic-free scatter into (B,sc)-sorted csr2 ----------------

__global__ void k_scatter(const int* __restrict__ esrc, const int* __restrict__ edst,
                          const uchar* __restrict__ rank8, const ushort* __restrict__ pB,
                          const int* __restrict__ bofs, int* __restrict__ csr2,
                          uchar* __restrict__ dloc8, int E, int BINS,
                          uint Mcsz, uint Msb) {
  const int i = blockIdx.x * 256 + threadIdx.x;
  if (i >= E) return;
  const int d = edst[i];
  const uint s = (uint)esrc[i];
  const uint sc = mdiv40(s, Mcsz);
  const int bin = (d >> 6) * SC + (int)sc;
  const uint sl = mdiv40((uint)i, Msb);
  const int pos = bofs[bin] + (int)pB[(size_t)sl * BINS + bin] + (int)rank8[i];
  csr2[pos] = (int)s;
  dloc8[pos] = (uchar)(d & 63);
}

// ---------------- prep: Wt[l][n][k] = f16(W_l[k][n]); CA/CB fold bias+BN ----------------

__global__ void k_prep(const float* __restrict__ W0, const float* __restrict__ W1,
                       const float* __restrict__ W2,
                       const float* __restrict__ b0, const float* __restrict__ b1,
                       const float* __restrict__ b2,
                       const float* __restrict__ g0, const float* __restrict__ be0,
                       const float* __restrict__ mu0, const float* __restrict__ vr0,
                       const float* __restrict__ g1, const float* __restrict__ be1,
                       const float* __restrict__ mu1, const float* __restrict__ vr1,
                       ushort* __restrict__ Wt, float* __restrict__ CA,
                       float* __restrict__ CB) {
  int b = blockIdx.x;
  if (b < 192) {
    int li = b * 256 + threadIdx.x;
    int l = li >> 14;
    int i = li & 16383;
    int n = i >> 7, k = i & 127;
    const float* W = (l == 0) ? W0 : ((l == 1) ? W1 : W2);
    Wt[li] = __half_as_ushort(__float2half_rn(W[k * D + n]));
  } else if (threadIdx.x < D) {
    int c = threadIdx.x;
    float A0 = g0[c] * rsqrtf(vr0[c] + 1e-5f);
    CA[c] = A0;
    CB[c] = (b0[c] - mu0[c]) * A0 + be0[c];
    float A1 = g1[c] * rsqrtf(vr1[c] + 1e-5f);
    CA[D + c] = A1;
    CB[D + c] = (b1[c] - mu1[c]) * A1 + be1[c];
    CA[2 * D + c] = 1.f;
    CB[2 * D + c] = b2[c];
  }
}

// ---------------- x16 = f16(x * ns) ----------------

__global__ void k_x16(const float* __restrict__ x, const float* __restrict__ ns,
                      uint* __restrict__ x16, int N) {
  int i = blockIdx.x * blockDim.x + threadIdx.x;
  if (i < N * 32) {
    int r = i >> 5;
    float4 v = reinterpret_cast<const float4*>(x)[i];
    float s = ns[r];
    uint2 u;
    u.x = pack_f16x2(v.x * s, v.y * s);
    u.y = pack_f16x2(v.z * s, v.w * s);
    reinterpret_cast<uint2*>(x16)[i] = u;
  }
}

// ---------------- MFMA GEMM (f16 in, f16 out) ----------------

__global__ __launch_bounds__(256) void k_gemm16(const ushort* __restrict__ A,
                                                const ushort* __restrict__ Wt,
                                                ushort* __restrict__ out, int M) {
  const int lane = threadIdx.x & 63;
  const int wv = threadIdx.x >> 6;
  const int m0 = (blockIdx.x * 4 + wv) * 32;
  if (m0 >= M) return;
  const int lr = lane & 15;
  const int kg = (lane >> 4) * 8;

  half8 hf[2][4];
  const half8 hz = {};
#pragma unroll
  for (int mt = 0; mt < 2; ++mt) {
    const int row = m0 + mt * 16 + lr;
    const bool ok = row < M;
#pragma unroll
    for (int kt = 0; kt < 4; ++kt)
      hf[mt][kt] = ok ? *reinterpret_cast<const half8*>(A + (size_t)row * D + kt * 32 + kg)
                      : hz;
  }

  f32x4 acc[8][2];
#pragma unroll
  for (int nt = 0; nt < 8; ++nt) {
    acc[nt][0] = (f32x4)(0.f);
    acc[nt][1] = (f32x4)(0.f);
  }

#pragma unroll
  for (int nt = 0; nt < 8; ++nt) {
    const ushort* wb = Wt + (size_t)(nt * 16 + lr) * D + kg;
#pragma unroll
    for (int kt = 0; kt < 4; ++kt) {
      half8 wf = *reinterpret_cast<const half8*>(wb + kt * 32);
      acc[nt][0] = __builtin_amdgcn_mfma_f32_16x16x32_f16(wf, hf[0][kt], acc[nt][0], 0, 0, 0);
      acc[nt][1] = __builtin_amdgcn_mfma_f32_16x16x32_f16(wf, hf[1][kt], acc[nt][1], 0, 0, 0);
    }
  }

  const int mo = lane & 15;
  const int no = (lane >> 4) * 4;
#pragma unroll
  for (int mt = 0; mt < 2; ++mt) {
    const int row = m0 + mt * 16 + mo;
    if (row < M) {
#pragma unroll
      for (int nt = 0; nt < 8; ++nt) {
        uint2 u;
        u.x = pack_f16x2(acc[nt][mt][0], acc[nt][mt][1]);
        u.y = pack_f16x2(acc[nt][mt][2], acc[nt][mt][3]);
        *reinterpret_cast<uint2*>(out + (size_t)row * D + nt * 16 + no) = u;
      }
    }
  }
}

// ---------------- chunk-synchronized SpMM: LDS f32 acc, src-chunk-ordered edges ----------
// Block owns 64 dst rows per sweep (2 sweeps, all blocks resident). csr2 sorted by
// (dst-block, src-chunk) -> whole machine gathers from the same 3.2 MB chunk together.

__global__ __launch_bounds__(256) void k_spmm_sync(const uint* __restrict__ hs,
                                                   const int* __restrict__ csr2,
                                                   const uchar* __restrict__ dloc8,
                                                   const int* __restrict__ bofs,
                                                   const float* __restrict__ nd,
                                                   const float* __restrict__ ns,
                                                   const float* __restrict__ CA,
                                                   const float* __restrict__ CB,
                                                   float* __restrict__ outf,
                                                   uint* __restrict__ hnext,
                                                   int N, int NB, int last) {
  __shared__ float accL[64 * 132];
  const int t = threadIdx.x;
  const int l = t & 63;
  const int c16 = l & 15;
  const int es = (t >> 6) * 4 + (l >> 4);  // 16 edge-slot groups per block

  for (int sweep = 0; sweep < 2; ++sweep) {
    const int B = sweep * NB + blockIdx.x;
    const int base = B * 64;
    if (base >= N) break;
    for (int j = t; j < 64 * 132; j += 256) accL[j] = 0.f;
    __syncthreads();
    const int b0 = bofs[B * 8];
    const int b8 = bofs[B * 8 + 8];
    for (int e = b0 + es; e < b8; e += 16) {
      const int src = csr2[e];
      const int dl = (int)dloc8[e];
      const uint4 v = *reinterpret_cast<const uint4*>(hs + (size_t)src * 64 + c16 * 4);
      float* a = accL + dl * 132 + c16 * 8;
      const float2 a0 = unpack_f16x2(v.x);
      const float2 a1 = unpack_f16x2(v.y);
      const float2 a2 = unpack_f16x2(v.z);
      const float2 a3 = unpack_f16x2(v.w);
      atomicAdd(a + 0, a0.x); atomicAdd(a + 1, a0.y);
      atomicAdd(a + 2, a1.x); atomicAdd(a + 3, a1.y);
      atomicAdd(a + 4, a2.x); atomicAdd(a + 5, a2.y);
      atomicAdd(a + 6, a3.x); atomicAdd(a + 7, a3.y);
    }
    __syncthreads();
    for (int j = t; j < 64 * 64; j += 256) {
      const int dl = j >> 6;
      const int up = j & 63;
      const int cp = up * 2;
      const int d = base + dl;
      if (d < N) {
        const float ndv = nd[d];
        float v0 = accL[dl * 132 + cp] * ndv * CA[cp] + CB[cp];
        float v1 = accL[dl * 132 + cp + 1] * ndv * CA[cp + 1] + CB[cp + 1];
        if (!last) {
          const float s = ns[d];
          v0 = fmaxf(v0, 0.f) * s;
          v1 = fmaxf(v1, 0.f) * s;
          hnext[(size_t)d * 64 + up] = pack_f16x2(v0, v1);
        } else {
          *reinterpret_cast<float2*>(outf + (size_t)d * D + cp) = make_float2(v0, v1);
        }
      }
    }
    __syncthreads();
  }
}

// ---------------- launch ----------------

extern "C" void kernel_launch(void* const* d_in, const int* in_sizes, int n_in,
                              void* d_out, int out_size, void* d_ws, size_t ws_size,
                              hipStream_t stream) {
  const float* x = (const float*)d_in[0];
  const int* esrc = (const int*)d_in[1];
  const int* edst = (const int*)d_in[2];
  const float* W0 = (const float*)d_in[3];
  const float* b0 = (const float*)d_in[4];
  const float* W1 = (const float*)d_in[5];
  const float* b1 = (const float*)d_in[6];
  const float* W2 = (const float*)d_in[7];
  const float* b2 = (const float*)d_in[8];
  const float* g0 = (const float*)d_in[9];
  const float* be0 = (const float*)d_in[10];
  const float* m0 = (const float*)d_in[11];
  const float* v0 = (const float*)d_in[12];
  const float* g1 = (const float*)d_in[13];
  const float* be1 = (const float*)d_in[14];
  const float* m1 = (const float*)d_in[15];
  const float* v1 = (const float*)d_in[16];
  const int N = in_sizes[0] / D;
  const int E = in_sizes[1];

  const int Bcnt = (N + 63) >> 6;
  const int NB = (Bcnt + 1) >> 1;
  const int BINS = Bcnt * SC;
  const int CSZ = (N + SC - 1) / SC;
  const int DB = (((N + NDC - 1) / NDC) + 1) & ~1;
  const int PBN = DB >> 1;
  const int SN = (((E + NSLN - 1) / NSLN) + 3) & ~3;
  const int SB = (E + NSLB - 1) / NSLB;
  const uint Mcsz = (uint)(((1ULL << 40) + (unsigned long long)CSZ - 1) / (unsigned long long)CSZ);
  const uint Msb = (uint)(((1ULL << 40) + (unsigned long long)SB - 1) / (unsigned long long)SB);

  char* p = (char*)d_ws;
  auto carve = [&](size_t bytes) {
    char* r = p;
    p += (bytes + 255) & ~(size_t)255;
    return (void*)r;
  };
  uint* hs16 = (uint*)carve((size_t)N * 64 * 4);
  ushort* Wt = (ushort*)carve((size_t)3 * D * D * 2);
  float* CA = (float*)carve((size_t)3 * D * 4);
  float* CB = (float*)carve((size_t)3 * D * 4);
  float* ns = (float*)carve((size_t)N * 4);
  float* nd = (float*)carve((size_t)N * 4);
  uint* pdN = (uint*)carve((size_t)NDC * NSLN * PBN * 4);
  uint* psN = (uint*)carve((size_t)NDC * NSLN * PBN * 4);
  ushort* pB = (ushort*)carve((size_t)NSLB * BINS * 2);
  uchar* rank8 = (uchar*)carve((size_t)E);
  int* btot = (int*)carve((size_t)BINS * 4);
  int* bofs = (int*)carve((size_t)(BINS + 1) * 4);
  const int nchB = (BINS + 1023) / 1024;
  int* csum = (int*)carve((size_t)nchB * 4);
  int* csr2 = (int*)carve((size_t)E * 4);
  uchar* dloc8 = (uchar*)carve((size_t)E);
  uint* bufA = (uint*)d_out;  // f16 GEMM-input ping buffer lives in d_out

  k_prep<<<193, 256, 0, stream>>>(W0, W1, W2, b0, b1, b2, g0, be0, m0, v0, g1, be1, m1, v1,
                                  Wt, CA, CB);
  k_histnode<<<NDC * NSLN, 1024, 0, stream>>>(esrc, edst, pdN, psN, E, N, DB, SN);
  k_histB<<<NSLB, 1024, 0, stream>>>(esrc, edst, pB, rank8, E, BINS, Mcsz, SB);
  k_reduceN<<<((N + 1) / 2 + 255) / 256, 256, 0, stream>>>(pdN, psN, ns, nd, N, DB);
  k_reduceB<<<(BINS + 255) / 256, 256, 0, stream>>>(pB, btot, BINS);
  k_scan_partial<<<nchB, 256, 0, stream>>>(btot, csum, BINS);
  k_scan_serial<<<1, 1, 0, stream>>>(csum, nchB, bofs, BINS);
  k_scan_final<<<nchB, 256, 0, stream>>>(btot, csum, bofs, BINS);
  k_scatter<<<(E + 255) / 256, 256, 0, stream>>>(esrc, edst, rank8, pB, bofs, csr2, dloc8,
                                                 E, BINS, Mcsz, Msb);
  k_x16<<<(N * 32 + 255) / 256, 256, 0, stream>>>(x, ns, bufA, N);

  const int gb = (N + 127) / 128;
  // layer 0
  k_gemm16<<<gb, 256, 0, stream>>>((const ushort*)bufA, Wt, (ushort*)hs16, N);
  k_spmm_sync<<<NB, 256, 0, stream>>>(hs16, csr2, dloc8, bofs, nd, ns, CA, CB,
                                      nullptr, bufA, N, NB, 0);
  // layer 1
  k_gemm16<<<gb, 256, 0, stream>>>((const ushort*)bufA, Wt + 16384, (ushort*)hs16, N);
  k_spmm_sync<<<NB, 256, 0, stream>>>(hs16, csr2, dloc8, bofs, nd, ns, CA + D, CB + D,
                                      nullptr, bufA, N, NB, 0);
  // layer 2
  k_gemm16<<<gb, 256, 0, stream>>>((const ushort*)bufA, Wt + 32768, (ushort*)hs16, N);
  k_spmm_sync<<<NB, 256, 0, stream>>>(hs16, csr2, dloc8, bofs, nd, ns, CA + 2 * D, CB + 2 * D,
                                      (float*)d_out, nullptr, N, NB, 1);
}

// Round 7
// 329.097 us; speedup vs baseline: 8.3341x; 8.3341x over previous
//
#include <hip/hip_runtime.h>
#include <hip/hip_fp16.h>
#include <math.h>

#define D 128
#define NCH 8          // node chunks
#define NSL 32         // edge slices
#define PBINS 6272     // packed uint counters per chunk (covers 12544 bins >= ceil(100000/8))

typedef _Float16 half8 __attribute__((ext_vector_type(8)));
typedef float f32x4 __attribute__((ext_vector_type(4)));

__device__ inline uint pack_f16x2(float a, float b) {
  __half2 h = __floats2half2_rn(a, b);
  return *reinterpret_cast<uint*>(&h);
}
__device__ inline float2 unpack_f16x2(uint p) {
  __half2 h = *reinterpret_cast<__half2*>(&p);
  return __half22float2(h);
}

// ---------------- histogram: chunked LDS, packed u16 counters, rank recording ----------------

__global__ __launch_bounds__(256) void k_hist(const int* __restrict__ esrc,
                                              const int* __restrict__ edst,
                                              uint* __restrict__ partial_d,
                                              uint* __restrict__ partial_s,
                                              ushort* __restrict__ rank16,
                                              int E, int N, int BPC, int S) {
  __shared__ uint hd[PBINS];
  __shared__ uint hsrc[PBINS];
  const int t = threadIdx.x;
  const int c = blockIdx.x / NSL;
  const int b = blockIdx.x % NSL;
  for (int j = t; j < PBINS; j += 256) { hd[j] = 0u; hsrc[j] = 0u; }
  __syncthreads();
  const int c0 = c * BPC;
  const int c1 = min(c0 + BPC, N);
  const int i0 = b * S;            // S is a multiple of 4 -> 4-aligned slice starts
  const int i1 = min(i0 + S, E);
  for (int vi = (i0 >> 2) + t; vi < ((i1 + 3) >> 2); vi += 256) {
    const int ib = vi << 2;
    int dv[4], sv[4];
    if (ib + 3 < i1) {
      const int4 d4 = reinterpret_cast<const int4*>(edst)[vi];
      const int4 s4 = reinterpret_cast<const int4*>(esrc)[vi];
      dv[0] = d4.x; dv[1] = d4.y; dv[2] = d4.z; dv[3] = d4.w;
      sv[0] = s4.x; sv[1] = s4.y; sv[2] = s4.z; sv[3] = s4.w;
    } else {
#pragma unroll
      for (int k = 0; k < 4; ++k) {
        dv[k] = (ib + k < i1) ? edst[ib + k] : -1;
        sv[k] = (ib + k < i1) ? esrc[ib + k] : -1;
      }
    }
#pragma unroll
    for (int k = 0; k < 4; ++k) {
      const int d = dv[k];
      if (d >= c0 && d < c1) {
        const uint bl = (uint)(d - c0);
        const uint sh = (bl & 1u) * 16u;
        const uint old = atomicAdd(&hd[bl >> 1], 1u << sh);
        rank16[ib + k] = (ushort)((old >> sh) & 0xffffu);
      }
      const int s = sv[k];
      if (s >= c0 && s < c1) {
        const uint bl = (uint)(s - c0);
        atomicAdd(&hsrc[bl >> 1], 1u << (16u * (bl & 1u)));
      }
    }
  }
  __syncthreads();
  uint* pd = partial_d + (size_t)blockIdx.x * PBINS;
  uint* ps = partial_s + (size_t)blockIdx.x * PBINS;
  for (int j = t; j < PBINS; j += 256) { pd[j] = hd[j]; ps[j] = hsrc[j]; }
}

// ---------------- reduce: totals, norms, exclusive prefix over slices (in place) ----------------

__global__ __launch_bounds__(256) void k_reduce(uint* __restrict__ partial_d,
                                                const uint* __restrict__ partial_s,
                                                int* __restrict__ totd,
                                                float* __restrict__ ns,
                                                float* __restrict__ nd, int N, int BPC) {
  const int j = blockIdx.x * 256 + threadIdx.x;  // packed-pair index (BPC is even)
  const int bin0 = j * 2;
  if (bin0 >= N) return;
  const int c = bin0 / BPC;
  const int jj = (bin0 - c * BPC) >> 1;
  uint* pd = partial_d + (size_t)c * NSL * PBINS + jj;
  const uint* ps = partial_s + (size_t)c * NSL * PBINS + jj;
  uint p0 = 0, p1 = 0, s0 = 0, s1 = 0;
#pragma unroll
  for (int b = 0; b < NSL; ++b) {
    const uint v = pd[(size_t)b * PBINS];
    pd[(size_t)b * PBINS] = p0 | (p1 << 16);
    p0 += v & 0xffffu; p1 += v >> 16;
    const uint w = ps[(size_t)b * PBINS];
    s0 += w & 0xffffu; s1 += w >> 16;
  }
  totd[bin0] = (int)p0;
  nd[bin0] = rsqrtf((float)max(p0, 1u));
  ns[bin0] = rsqrtf((float)max(s0, 1u));
  if (bin0 + 1 < N) {
    totd[bin0 + 1] = (int)p1;
    nd[bin0 + 1] = rsqrtf((float)max(p1, 1u));
    ns[bin0 + 1] = rsqrtf((float)max(s1, 1u));
  }
}

// ---------------- rofs scan over totd ----------------

__global__ __launch_bounds__(256) void k_scan_partial(const int* __restrict__ totd,
                                                      int* __restrict__ csum, int n) {
  __shared__ int sd[256];
  const int b = blockIdx.x, t = threadIdx.x;
  const int base = b * 1024 + t * 4;
  int s = 0;
#pragma unroll
  for (int i = 0; i < 4; ++i) { int idx = base + i; if (idx < n) s += totd[idx]; }
  sd[t] = s; __syncthreads();
  for (int off = 128; off > 0; off >>= 1) {
    if (t < off) sd[t] += sd[t + off];
    __syncthreads();
  }
  if (t == 0) csum[b] = sd[0];
}

__global__ void k_scan_serial(int* __restrict__ csum, int nch,
                              int* __restrict__ rofs, int n) {
  if (blockIdx.x == 0 && threadIdx.x == 0) {
    int run = 0;
    for (int b = 0; b < nch; ++b) { int v = csum[b]; csum[b] = run; run += v; }
    rofs[n] = run;
  }
}

__global__ __launch_bounds__(256) void k_scan_final(const int* __restrict__ totd,
                                                    const int* __restrict__ csum,
                                                    int* __restrict__ rofs, int n) {
  __shared__ int sd[256];
  const int b = blockIdx.x, t = threadIdx.x;
  const int base = b * 1024 + t * 4;
  int v[4]; int s = 0;
#pragma unroll
  for (int i = 0; i < 4; ++i) { v[i] = (base + i < n) ? totd[base + i] : 0; s += v[i]; }
  sd[t] = s; __syncthreads();
  for (int off = 1; off < 256; off <<= 1) {
    int x = (t >= off) ? sd[t - off] : 0;
    __syncthreads();
    sd[t] += x;
    __syncthreads();
  }
  int o = sd[t] - s + csum[b];
#pragma unroll
  for (int i = 0; i < 4; ++i) {
    if (base + i < n) { rofs[base + i] = o; o += v[i]; }
  }
}

// ---------------- atomic-free scatter ----------------

__global__ void k_scatter2(const int* __restrict__ esrc, const int* __restrict__ edst,
                           const ushort* __restrict__ rank16,
                           const uint* __restrict__ partial_d,
                           const int* __restrict__ rofs, int* __restrict__ csr,
                           int E, int BPC, int S) {
  const int i = blockIdx.x * 256 + threadIdx.x;
  if (i >= E) return;
  const int d = edst[i];
  const int c = d / BPC;
  const uint bl = (uint)(d - c * BPC);
  const int b = i / S;
  const uint pr = partial_d[(size_t)(c * NSL + b) * PBINS + (bl >> 1)];
  const uint p = (bl & 1u) ? (pr >> 16) : (pr & 0xffffu);
  csr[rofs[d] + (int)p + (int)rank16[i]] = esrc[i];
}

// ---------------- prep: Wt[l][n][k] = f16(W_l[k][n]); CA/CB fold bias+BN ----------------

__global__ void k_prep(const float* __restrict__ W0, const float* __restrict__ W1,
                       const float* __restrict__ W2,
                       const float* __restrict__ b0, const float* __restrict__ b1,
                       const float* __restrict__ b2,
                       const float* __restrict__ g0, const float* __restrict__ be0,
                       const float* __restrict__ mu0, const float* __restrict__ vr0,
                       const float* __restrict__ g1, const float* __restrict__ be1,
                       const float* __restrict__ mu1, const float* __restrict__ vr1,
                       ushort* __restrict__ Wt, float* __restrict__ CA,
                       float* __restrict__ CB) {
  int b = blockIdx.x;
  if (b < 192) {
    int li = b * 256 + threadIdx.x;
    int l = li >> 14;
    int i = li & 16383;
    int n = i >> 7, k = i & 127;
    const float* W = (l == 0) ? W0 : ((l == 1) ? W1 : W2);
    Wt[li] = __half_as_ushort(__float2half_rn(W[k * D + n]));
  } else if (threadIdx.x < D) {
    int c = threadIdx.x;
    float A0 = g0[c] * rsqrtf(vr0[c] + 1e-5f);
    CA[c] = A0;
    CB[c] = (b0[c] - mu0[c]) * A0 + be0[c];
    float A1 = g1[c] * rsqrtf(vr1[c] + 1e-5f);
    CA[D + c] = A1;
    CB[D + c] = (b1[c] - mu1[c]) * A1 + be1[c];
    CA[2 * D + c] = 1.f;
    CB[2 * D + c] = b2[c];
  }
}

// ---------------- x16 = f16(x * ns) ----------------

__global__ void k_x16(const float* __restrict__ x, const float* __restrict__ ns,
                      uint* __restrict__ x16, int N) {
  int i = blockIdx.x * blockDim.x + threadIdx.x;
  if (i < N * 32) {
    int r = i >> 5;
    float4 v = reinterpret_cast<const float4*>(x)[i];
    float s = ns[r];
    uint2 u;
    u.x = pack_f16x2(v.x * s, v.y * s);
    u.y = pack_f16x2(v.z * s, v.w * s);
    reinterpret_cast<uint2*>(x16)[i] = u;
  }
}

// ---------------- MFMA GEMM (f16 in, f16 out) ----------------

__global__ __launch_bounds__(256) void k_gemm16(const ushort* __restrict__ A,
                                                const ushort* __restrict__ Wt,
                                                ushort* __restrict__ out, int M) {
  const int lane = threadIdx.x & 63;
  const int wv = threadIdx.x >> 6;
  const int m0 = (blockIdx.x * 4 + wv) * 32;
  if (m0 >= M) return;
  const int lr = lane & 15;
  const int kg = (lane >> 4) * 8;

  half8 hf[2][4];
  const half8 hz = {};
#pragma unroll
  for (int mt = 0; mt < 2; ++mt) {
    const int row = m0 + mt * 16 + lr;
    const bool ok = row < M;
#pragma unroll
    for (int kt = 0; kt < 4; ++kt)
      hf[mt][kt] = ok ? *reinterpret_cast<const half8*>(A + (size_t)row * D + kt * 32 + kg)
                      : hz;
  }

  f32x4 acc[8][2];
#pragma unroll
  for (int nt = 0; nt < 8; ++nt) {
    acc[nt][0] = (f32x4)(0.f);
    acc[nt][1] = (f32x4)(0.f);
  }

#pragma unroll
  for (int nt = 0; nt < 8; ++nt) {
    const ushort* wb = Wt + (size_t)(nt * 16 + lr) * D + kg;
#pragma unroll
    for (int kt = 0; kt < 4; ++kt) {
      half8 wf = *reinterpret_cast<const half8*>(wb + kt * 32);
      acc[nt][0] = __builtin_amdgcn_mfma_f32_16x16x32_f16(wf, hf[0][kt], acc[nt][0], 0, 0, 0);
      acc[nt][1] = __builtin_amdgcn_mfma_f32_16x16x32_f16(wf, hf[1][kt], acc[nt][1], 0, 0, 0);
    }
  }

  const int mo = lane & 15;
  const int no = (lane >> 4) * 4;
#pragma unroll
  for (int mt = 0; mt < 2; ++mt) {
    const int row = m0 + mt * 16 + mo;
    if (row < M) {
#pragma unroll
      for (int nt = 0; nt < 8; ++nt) {
        uint2 u;
        u.x = pack_f16x2(acc[nt][mt][0], acc[nt][mt][1]);
        u.y = pack_f16x2(acc[nt][mt][2], acc[nt][mt][3]);
        *reinterpret_cast<uint2*>(out + (size_t)row * D + nt * 16 + no) = u;
      }
    }
  }
}

// ---------------- SpMM: wave/dst row; exec-safe index prefetch + shfl; 16Bx16-lane gather ----

__global__ __launch_bounds__(256) void k_spmm16(const uint* __restrict__ hs,
                                                const int* __restrict__ csr,
                                                const int* __restrict__ rofs,
                                                const float* __restrict__ nd,
                                                const float* __restrict__ ns,
                                                const float* __restrict__ CA,
                                                const float* __restrict__ CB,
                                                float* __restrict__ outf,
                                                uint* __restrict__ hnext,
                                                int N, int last) {
  const int t = threadIdx.x;
  const int lane = t & 63;
  const int d = blockIdx.x * 4 + (t >> 6);
  if (d >= N) return;
  const int sub = lane >> 4;   // edge slot 0..3
  const int c16 = lane & 15;   // 8-col group
  const int beg = rofs[d], end = rofs[d + 1];

  float acc[8];
#pragma unroll
  for (int j = 0; j < 8; ++j) acc[j] = 0.f;

  for (int base = beg; base < end; base += 64) {
    const int len = min(64, end - base);
    // one coalesced per-wave load of up to 64 indices; gathers then have no
    // memory-address dependency (index via shfl) -> deep MLP.
    int idx = 0;
    if (lane < len) idx = csr[base + lane];
    // Wave-uniform loop bound: ALL 64 lanes stay active at the __shfl so the
    // source lane is never exec-inactive (R6 bug: divergent tail made
    // ds_bpermute read disabled lanes -> undefined). Gather is predicated.
    const int lenR = (len + 3) & ~3;
    for (int j = sub; j < lenR; j += 4) {
      const int s = __shfl(idx, j);
      if (j < len) {
        const uint4 v = *reinterpret_cast<const uint4*>(hs + (size_t)s * 64 + c16 * 4);
        const float2 a0 = unpack_f16x2(v.x);
        const float2 a1 = unpack_f16x2(v.y);
        const float2 a2 = unpack_f16x2(v.z);
        const float2 a3 = unpack_f16x2(v.w);
        acc[0] += a0.x; acc[1] += a0.y;
        acc[2] += a1.x; acc[3] += a1.y;
        acc[4] += a2.x; acc[5] += a2.y;
        acc[6] += a3.x; acc[7] += a3.y;
      }
    }
  }
#pragma unroll
  for (int j = 0; j < 8; ++j) {
    acc[j] += __shfl_xor(acc[j], 16);
    acc[j] += __shfl_xor(acc[j], 32);
  }
  if (sub == 0) {
    const float ndv = nd[d];
    const float4 ca0 = *reinterpret_cast<const float4*>(CA + c16 * 8);
    const float4 ca1 = *reinterpret_cast<const float4*>(CA + c16 * 8 + 4);
    const float4 cb0 = *reinterpret_cast<const float4*>(CB + c16 * 8);
    const float4 cb1 = *reinterpret_cast<const float4*>(CB + c16 * 8 + 4);
    float r[8];
    r[0] = acc[0] * ndv * ca0.x + cb0.x;
    r[1] = acc[1] * ndv * ca0.y + cb0.y;
    r[2] = acc[2] * ndv * ca0.z + cb0.z;
    r[3] = acc[3] * ndv * ca0.w + cb0.w;
    r[4] = acc[4] * ndv * ca1.x + cb1.x;
    r[5] = acc[5] * ndv * ca1.y + cb1.y;
    r[6] = acc[6] * ndv * ca1.z + cb1.z;
    r[7] = acc[7] * ndv * ca1.w + cb1.w;
    if (!last) {
      const float s = ns[d];
#pragma unroll
      for (int j = 0; j < 8; ++j) r[j] = fmaxf(r[j], 0.f) * s;
      uint4 u;
      u.x = pack_f16x2(r[0], r[1]);
      u.y = pack_f16x2(r[2], r[3]);
      u.z = pack_f16x2(r[4], r[5]);
      u.w = pack_f16x2(r[6], r[7]);
      *reinterpret_cast<uint4*>(hnext + (size_t)d * 64 + c16 * 4) = u;
    } else {
      float4 o0 = make_float4(r[0], r[1], r[2], r[3]);
      float4 o1 = make_float4(r[4], r[5], r[6], r[7]);
      *reinterpret_cast<float4*>(outf + (size_t)d * D + c16 * 8) = o0;
      *reinterpret_cast<float4*>(outf + (size_t)d * D + c16 * 8 + 4) = o1;
    }
  }
}

// ---------------- launch ----------------

extern "C" void kernel_launch(void* const* d_in, const int* in_sizes, int n_in,
                              void* d_out, int out_size, void* d_ws, size_t ws_size,
                              hipStream_t stream) {
  const float* x = (const float*)d_in[0];
  const int* esrc = (const int*)d_in[1];
  const int* edst = (const int*)d_in[2];
  const float* W0 = (const float*)d_in[3];
  const float* b0 = (const float*)d_in[4];
  const float* W1 = (const float*)d_in[5];
  const float* b1 = (const float*)d_in[6];
  const float* W2 = (const float*)d_in[7];
  const float* b2 = (const float*)d_in[8];
  const float* g0 = (const float*)d_in[9];
  const float* be0 = (const float*)d_in[10];
  const float* m0 = (const float*)d_in[11];
  const float* v0 = (const float*)d_in[12];
  const float* g1 = (const float*)d_in[13];
  const float* be1 = (const float*)d_in[14];
  const float* m1 = (const float*)d_in[15];
  const float* v1 = (const float*)d_in[16];
  const int N = in_sizes[0] / D;
  const int E = in_sizes[1];

  const int BPC = (((N + NCH - 1) / NCH) + 1) & ~1;        // even bins/chunk (<= 12544)
  const int S = (((E + NSL - 1) / NSL) + 3) & ~3;          // 4-aligned slice size

  char* p = (char*)d_ws;
  auto carve = [&](size_t bytes) {
    char* r = p;
    p += (bytes + 255) & ~(size_t)255;
    return (void*)r;
  };
  uint* hs16 = (uint*)carve((size_t)N * 64 * 4);           // GEMM out / SpMM in (f16 packed)
  ushort* Wt = (ushort*)carve((size_t)3 * D * D * 2);
  float* CA = (float*)carve((size_t)3 * D * 4);
  float* CB = (float*)carve((size_t)3 * D * 4);
  float* ns = (float*)carve((size_t)N * 4);
  float* nd = (float*)carve((size_t)N * 4);
  uint* partial_d = (uint*)carve((size_t)NCH * NSL * PBINS * 4);
  uint* partial_s = (uint*)carve((size_t)NCH * NSL * PBINS * 4);
  ushort* rank16 = (ushort*)carve((size_t)E * 2);
  int* totd = (int*)carve((size_t)N * 4);
  int* rofs = (int*)carve((size_t)(N + 1) * 4);
  const int nch = (N + 1023) / 1024;
  int* csum = (int*)carve((size_t)nch * 4);
  int* csr = (int*)carve((size_t)E * 4);
  uint* bufA = (uint*)d_out;  // GEMM input ping buffer lives in d_out (fully rewritten)

  k_prep<<<193, 256, 0, stream>>>(W0, W1, W2, b0, b1, b2, g0, be0, m0, v0, g1, be1, m1, v1,
                                  Wt, CA, CB);
  k_hist<<<NCH * NSL, 256, 0, stream>>>(esrc, edst, partial_d, partial_s, rank16, E, N, BPC, S);
  k_reduce<<<((N + 1) / 2 + 255) / 256, 256, 0, stream>>>(partial_d, partial_s, totd, ns, nd,
                                                          N, BPC);
  k_scan_partial<<<nch, 256, 0, stream>>>(totd, csum, N);
  k_scan_serial<<<1, 1, 0, stream>>>(csum, nch, rofs, N);
  k_scan_final<<<nch, 256, 0, stream>>>(totd, csum, rofs, N);
  k_scatter2<<<(E + 255) / 256, 256, 0, stream>>>(esrc, edst, rank16, partial_d, rofs, csr,
                                                  E, BPC, S);
  k_x16<<<(N * 32 + 255) / 256, 256, 0, stream>>>(x, ns, bufA, N);

  const int gb = (N + 127) / 128;
  const int sb = (N + 3) / 4;
  // layer 0
  k_gemm16<<<gb, 256, 0, stream>>>((const ushort*)bufA, Wt, (ushort*)hs16, N);
  k_spmm16<<<sb, 256, 0, stream>>>(hs16, csr, rofs, nd, ns, CA, CB, nullptr, bufA, N, 0);
  // layer 1
  k_gemm16<<<gb, 256, 0, stream>>>((const ushort*)bufA, Wt + 16384, (ushort*)hs16, N);
  k_spmm16<<<sb, 256, 0, stream>>>(hs16, csr, rofs, nd, ns, CA + D, CB + D, nullptr, bufA, N, 0);
  // layer 2
  k_gemm16<<<gb, 256, 0, stream>>>((const ushort*)bufA, Wt + 32768, (ushort*)hs16, N);
  k_spmm16<<<sb, 256, 0, stream>>>(hs16, csr, rofs, nd, ns, CA + 2 * D, CB + 2 * D,
                                   (float*)d_out, nullptr, N, 1);
}

// Round 8
// 295.127 us; speedup vs baseline: 9.2934x; 1.1151x over previous
//
#include <hip/hip_runtime.h>
#include <hip/hip_fp16.h>
#include <math.h>

#define D 128
#define NCH 8          // node chunks
#define NSL 32         // edge slices
#define PBINS 6272     // packed uint counters per chunk (covers 12544 bins >= ceil(100000/8))

typedef _Float16 half8 __attribute__((ext_vector_type(8)));
typedef float f32x4 __attribute__((ext_vector_type(4)));

__device__ inline uint pack_f16x2(float a, float b) {
  __half2 h = __floats2half2_rn(a, b);
  return *reinterpret_cast<uint*>(&h);
}
__device__ inline float2 unpack_f16x2(uint p) {
  __half2 h = *reinterpret_cast<__half2*>(&p);
  return __half22float2(h);
}

// ---------------- histogram: chunked LDS, packed u16 counters, rank recording ----------------

__global__ __launch_bounds__(256) void k_hist(const int* __restrict__ esrc,
                                              const int* __restrict__ edst,
                                              uint* __restrict__ partial_d,
                                              uint* __restrict__ partial_s,
                                              ushort* __restrict__ rank16,
                                              int E, int N, int BPC, int S) {
  __shared__ uint hd[PBINS];
  __shared__ uint hsrc[PBINS];
  const int t = threadIdx.x;
  const int c = blockIdx.x / NSL;
  const int b = blockIdx.x % NSL;
  for (int j = t; j < PBINS; j += 256) { hd[j] = 0u; hsrc[j] = 0u; }
  __syncthreads();
  const int c0 = c * BPC;
  const int c1 = min(c0 + BPC, N);
  const int i0 = b * S;            // S is a multiple of 4 -> 4-aligned slice starts
  const int i1 = min(i0 + S, E);
  for (int vi = (i0 >> 2) + t; vi < ((i1 + 3) >> 2); vi += 256) {
    const int ib = vi << 2;
    int dv[4], sv[4];
    if (ib + 3 < i1) {
      const int4 d4 = reinterpret_cast<const int4*>(edst)[vi];
      const int4 s4 = reinterpret_cast<const int4*>(esrc)[vi];
      dv[0] = d4.x; dv[1] = d4.y; dv[2] = d4.z; dv[3] = d4.w;
      sv[0] = s4.x; sv[1] = s4.y; sv[2] = s4.z; sv[3] = s4.w;
    } else {
#pragma unroll
      for (int k = 0; k < 4; ++k) {
        dv[k] = (ib + k < i1) ? edst[ib + k] : -1;
        sv[k] = (ib + k < i1) ? esrc[ib + k] : -1;
      }
    }
#pragma unroll
    for (int k = 0; k < 4; ++k) {
      const int d = dv[k];
      if (d >= c0 && d < c1) {
        const uint bl = (uint)(d - c0);
        const uint sh = (bl & 1u) * 16u;
        const uint old = atomicAdd(&hd[bl >> 1], 1u << sh);
        rank16[ib + k] = (ushort)((old >> sh) & 0xffffu);
      }
      const int s = sv[k];
      if (s >= c0 && s < c1) {
        const uint bl = (uint)(s - c0);
        atomicAdd(&hsrc[bl >> 1], 1u << (16u * (bl & 1u)));
      }
    }
  }
  __syncthreads();
  uint* pd = partial_d + (size_t)blockIdx.x * PBINS;
  uint* ps = partial_s + (size_t)blockIdx.x * PBINS;
  for (int j = t; j < PBINS; j += 256) { pd[j] = hd[j]; ps[j] = hsrc[j]; }
}

// ---------------- reduce: totals, norms, exclusive prefix over slices (in place) ----------------

__global__ __launch_bounds__(256) void k_reduce(uint* __restrict__ partial_d,
                                                const uint* __restrict__ partial_s,
                                                int* __restrict__ totd,
                                                float* __restrict__ ns,
                                                float* __restrict__ nd, int N, int BPC) {
  const int j = blockIdx.x * 256 + threadIdx.x;  // packed-pair index (BPC is even)
  const int bin0 = j * 2;
  if (bin0 >= N) return;
  const int c = bin0 / BPC;
  const int jj = (bin0 - c * BPC) >> 1;
  uint* pd = partial_d + (size_t)c * NSL * PBINS + jj;
  const uint* ps = partial_s + (size_t)c * NSL * PBINS + jj;
  uint p0 = 0, p1 = 0, s0 = 0, s1 = 0;
#pragma unroll
  for (int b = 0; b < NSL; ++b) {
    const uint v = pd[(size_t)b * PBINS];
    pd[(size_t)b * PBINS] = p0 | (p1 << 16);
    p0 += v & 0xffffu; p1 += v >> 16;
    const uint w = ps[(size_t)b * PBINS];
    s0 += w & 0xffffu; s1 += w >> 16;
  }
  totd[bin0] = (int)p0;
  nd[bin0] = rsqrtf((float)max(p0, 1u));
  ns[bin0] = rsqrtf((float)max(s0, 1u));
  if (bin0 + 1 < N) {
    totd[bin0 + 1] = (int)p1;
    nd[bin0 + 1] = rsqrtf((float)max(p1, 1u));
    ns[bin0 + 1] = rsqrtf((float)max(s1, 1u));
  }
}

// ---------------- rofs scan over totd ----------------

__global__ __launch_bounds__(256) void k_scan_partial(const int* __restrict__ totd,
                                                      int* __restrict__ csum, int n) {
  __shared__ int sd[256];
  const int b = blockIdx.x, t = threadIdx.x;
  const int base = b * 1024 + t * 4;
  int s = 0;
#pragma unroll
  for (int i = 0; i < 4; ++i) { int idx = base + i; if (idx < n) s += totd[idx]; }
  sd[t] = s; __syncthreads();
  for (int off = 128; off > 0; off >>= 1) {
    if (t < off) sd[t] += sd[t + off];
    __syncthreads();
  }
  if (t == 0) csum[b] = sd[0];
}

__global__ void k_scan_serial(int* __restrict__ csum, int nch,
                              int* __restrict__ rofs, int n) {
  if (blockIdx.x == 0 && threadIdx.x == 0) {
    int run = 0;
    for (int b = 0; b < nch; ++b) { int v = csum[b]; csum[b] = run; run += v; }
    rofs[n] = run;
  }
}

__global__ __launch_bounds__(256) void k_scan_final(const int* __restrict__ totd,
                                                    const int* __restrict__ csum,
                                                    int* __restrict__ rofs, int n) {
  __shared__ int sd[256];
  const int b = blockIdx.x, t = threadIdx.x;
  const int base = b * 1024 + t * 4;
  int v[4]; int s = 0;
#pragma unroll
  for (int i = 0; i < 4; ++i) { v[i] = (base + i < n) ? totd[base + i] : 0; s += v[i]; }
  sd[t] = s; __syncthreads();
  for (int off = 1; off < 256; off <<= 1) {
    int x = (t >= off) ? sd[t - off] : 0;
    __syncthreads();
    sd[t] += x;
    __syncthreads();
  }
  int o = sd[t] - s + csum[b];
#pragma unroll
  for (int i = 0; i < 4; ++i) {
    if (base + i < n) { rofs[base + i] = o; o += v[i]; }
  }
}

// ---------------- atomic-free scatter ----------------

__global__ void k_scatter2(const int* __restrict__ esrc, const int* __restrict__ edst,
                           const ushort* __restrict__ rank16,
                           const uint* __restrict__ partial_d,
                           const int* __restrict__ rofs, int* __restrict__ csr,
                           int E, int BPC, int S) {
  const int i = blockIdx.x * 256 + threadIdx.x;
  if (i >= E) return;
  const int d = edst[i];
  const int c = d / BPC;
  const uint bl = (uint)(d - c * BPC);
  const int b = i / S;
  const uint pr = partial_d[(size_t)(c * NSL + b) * PBINS + (bl >> 1)];
  const uint p = (bl & 1u) ? (pr >> 16) : (pr & 0xffffu);
  csr[rofs[d] + (int)p + (int)rank16[i]] = esrc[i];
}

// ---------------- prep: Wt[l][n][k] = f16(W_l[k][n]); CA/CB fold bias+BN ----------------

__global__ void k_prep(const float* __restrict__ W0, const float* __restrict__ W1,
                       const float* __restrict__ W2,
                       const float* __restrict__ b0, const float* __restrict__ b1,
                       const float* __restrict__ b2,
                       const float* __restrict__ g0, const float* __restrict__ be0,
                       const float* __restrict__ mu0, const float* __restrict__ vr0,
                       const float* __restrict__ g1, const float* __restrict__ be1,
                       const float* __restrict__ mu1, const float* __restrict__ vr1,
                       ushort* __restrict__ Wt, float* __restrict__ CA,
                       float* __restrict__ CB) {
  int b = blockIdx.x;
  if (b < 192) {
    int li = b * 256 + threadIdx.x;
    int l = li >> 14;
    int i = li & 16383;
    int n = i >> 7, k = i & 127;
    const float* W = (l == 0) ? W0 : ((l == 1) ? W1 : W2);
    Wt[li] = __half_as_ushort(__float2half_rn(W[k * D + n]));
  } else if (threadIdx.x < D) {
    int c = threadIdx.x;
    float A0 = g0[c] * rsqrtf(vr0[c] + 1e-5f);
    CA[c] = A0;
    CB[c] = (b0[c] - mu0[c]) * A0 + be0[c];
    float A1 = g1[c] * rsqrtf(vr1[c] + 1e-5f);
    CA[D + c] = A1;
    CB[D + c] = (b1[c] - mu1[c]) * A1 + be1[c];
    CA[2 * D + c] = 1.f;
    CB[2 * D + c] = b2[c];
  }
}

// ---------------- x16 = f16(x * ns) ----------------

__global__ void k_x16(const float* __restrict__ x, const float* __restrict__ ns,
                      uint* __restrict__ x16, int N) {
  int i = blockIdx.x * blockDim.x + threadIdx.x;
  if (i < N * 32) {
    int r = i >> 5;
    float4 v = reinterpret_cast<const float4*>(x)[i];
    float s = ns[r];
    uint2 u;
    u.x = pack_f16x2(v.x * s, v.y * s);
    u.y = pack_f16x2(v.z * s, v.w * s);
    reinterpret_cast<uint2*>(x16)[i] = u;
  }
}

// ---------------- MFMA GEMM (f16 in, f16 out) ----------------

__global__ __launch_bounds__(256) void k_gemm16(const ushort* __restrict__ A,
                                                const ushort* __restrict__ Wt,
                                                ushort* __restrict__ out, int M) {
  const int lane = threadIdx.x & 63;
  const int wv = threadIdx.x >> 6;
  const int m0 = (blockIdx.x * 4 + wv) * 32;
  if (m0 >= M) return;
  const int lr = lane & 15;
  const int kg = (lane >> 4) * 8;

  half8 hf[2][4];
  const half8 hz = {};
#pragma unroll
  for (int mt = 0; mt < 2; ++mt) {
    const int row = m0 + mt * 16 + lr;
    const bool ok = row < M;
#pragma unroll
    for (int kt = 0; kt < 4; ++kt)
      hf[mt][kt] = ok ? *reinterpret_cast<const half8*>(A + (size_t)row * D + kt * 32 + kg)
                      : hz;
  }

  f32x4 acc[8][2];
#pragma unroll
  for (int nt = 0; nt < 8; ++nt) {
    acc[nt][0] = (f32x4)(0.f);
    acc[nt][1] = (f32x4)(0.f);
  }

#pragma unroll
  for (int nt = 0; nt < 8; ++nt) {
    const ushort* wb = Wt + (size_t)(nt * 16 + lr) * D + kg;
#pragma unroll
    for (int kt = 0; kt < 4; ++kt) {
      half8 wf = *reinterpret_cast<const half8*>(wb + kt * 32);
      acc[nt][0] = __builtin_amdgcn_mfma_f32_16x16x32_f16(wf, hf[0][kt], acc[nt][0], 0, 0, 0);
      acc[nt][1] = __builtin_amdgcn_mfma_f32_16x16x32_f16(wf, hf[1][kt], acc[nt][1], 0, 0, 0);
    }
  }

  const int mo = lane & 15;
  const int no = (lane >> 4) * 4;
#pragma unroll
  for (int mt = 0; mt < 2; ++mt) {
    const int row = m0 + mt * 16 + mo;
    if (row < M) {
#pragma unroll
      for (int nt = 0; nt < 8; ++nt) {
        uint2 u;
        u.x = pack_f16x2(acc[nt][mt][0], acc[nt][mt][1]);
        u.y = pack_f16x2(acc[nt][mt][2], acc[nt][mt][3]);
        *reinterpret_cast<uint2*>(out + (size_t)row * D + nt * 16 + no) = u;
      }
    }
  }
}

// ---------------- SpMM: 16-lane group per dst row (4 rows/wave), no cross-slot reduce ----
// Group's 16 lanes cover all 128 cols (8/lane). Edge gathers 4-unrolled with clamped
// index + 0/1-weight FMA: flat control flow, all gathers issue -> deep MLP per wave.

__global__ __launch_bounds__(256) void k_spmm16(const uint* __restrict__ hs,
                                                const int* __restrict__ csr,
                                                const int* __restrict__ rofs,
                                                const float* __restrict__ nd,
                                                const float* __restrict__ ns,
                                                const float* __restrict__ CA,
                                                const float* __restrict__ CB,
                                                float* __restrict__ outf,
                                                uint* __restrict__ hnext,
                                                int N, int last) {
  const int t = threadIdx.x;
  const int lane = t & 63;
  const int c16 = lane & 15;       // col group: this lane owns cols c16*8..c16*8+7
  const int gb = lane & ~15;       // group's base lane within the wave
  const int d = blockIdx.x * 16 + (t >> 4);
  if (d >= N) return;              // uniform per 16-lane group; shfl stays intra-group
  const int beg = rofs[d], end = rofs[d + 1];

  float acc[8];
#pragma unroll
  for (int j = 0; j < 8; ++j) acc[j] = 0.f;

  for (int base = beg; base < end; base += 16) {
    const int len = min(16, end - base);
    // 16-lane coalesced index load (clamped -> always defined for shfl)
    const int idx = csr[min(base + c16, end - 1)];
#pragma unroll 1
    for (int j = 0; j < len; j += 4) {
      // clamped source slots: tail gathers duplicate the last edge (L1 hit),
      // accumulation weighted 0 so the sum is exact; control flow stays flat.
      const int l1 = min(j + 1, len - 1), l2 = min(j + 2, len - 1), l3 = min(j + 3, len - 1);
      const int s0 = __shfl(idx, gb + j);
      const int s1 = __shfl(idx, gb + l1);
      const int s2 = __shfl(idx, gb + l2);
      const int s3 = __shfl(idx, gb + l3);
      const float w1 = (j + 1 < len) ? 1.f : 0.f;
      const float w2 = (j + 2 < len) ? 1.f : 0.f;
      const float w3 = (j + 3 < len) ? 1.f : 0.f;
      const uint4 v0 = *reinterpret_cast<const uint4*>(hs + (size_t)s0 * 64 + c16 * 4);
      const uint4 v1 = *reinterpret_cast<const uint4*>(hs + (size_t)s1 * 64 + c16 * 4);
      const uint4 v2 = *reinterpret_cast<const uint4*>(hs + (size_t)s2 * 64 + c16 * 4);
      const uint4 v3 = *reinterpret_cast<const uint4*>(hs + (size_t)s3 * 64 + c16 * 4);
#pragma unroll
      for (int q = 0; q < 4; ++q) {
        const uint u0 = (&v0.x)[q], u1 = (&v1.x)[q], u2 = (&v2.x)[q], u3 = (&v3.x)[q];
        const float2 a0 = unpack_f16x2(u0);
        const float2 a1 = unpack_f16x2(u1);
        const float2 a2 = unpack_f16x2(u2);
        const float2 a3 = unpack_f16x2(u3);
        acc[q * 2]     += a0.x;
        acc[q * 2 + 1] += a0.y;
        acc[q * 2]     = fmaf(a1.x, w1, acc[q * 2]);
        acc[q * 2 + 1] = fmaf(a1.y, w1, acc[q * 2 + 1]);
        acc[q * 2]     = fmaf(a2.x, w2, acc[q * 2]);
        acc[q * 2 + 1] = fmaf(a2.y, w2, acc[q * 2 + 1]);
        acc[q * 2]     = fmaf(a3.x, w3, acc[q * 2]);
        acc[q * 2 + 1] = fmaf(a3.y, w3, acc[q * 2 + 1]);
      }
    }
  }

  const float ndv = nd[d];
  const float4 ca0 = *reinterpret_cast<const float4*>(CA + c16 * 8);
  const float4 ca1 = *reinterpret_cast<const float4*>(CA + c16 * 8 + 4);
  const float4 cb0 = *reinterpret_cast<const float4*>(CB + c16 * 8);
  const float4 cb1 = *reinterpret_cast<const float4*>(CB + c16 * 8 + 4);
  float r[8];
  r[0] = acc[0] * ndv * ca0.x + cb0.x;
  r[1] = acc[1] * ndv * ca0.y + cb0.y;
  r[2] = acc[2] * ndv * ca0.z + cb0.z;
  r[3] = acc[3] * ndv * ca0.w + cb0.w;
  r[4] = acc[4] * ndv * ca1.x + cb1.x;
  r[5] = acc[5] * ndv * ca1.y + cb1.y;
  r[6] = acc[6] * ndv * ca1.z + cb1.z;
  r[7] = acc[7] * ndv * ca1.w + cb1.w;
  if (!last) {
    const float s = ns[d];
#pragma unroll
    for (int j = 0; j < 8; ++j) r[j] = fmaxf(r[j], 0.f) * s;
    uint4 u;
    u.x = pack_f16x2(r[0], r[1]);
    u.y = pack_f16x2(r[2], r[3]);
    u.z = pack_f16x2(r[4], r[5]);
    u.w = pack_f16x2(r[6], r[7]);
    *reinterpret_cast<uint4*>(hnext + (size_t)d * 64 + c16 * 4) = u;
  } else {
    float4 o0 = make_float4(r[0], r[1], r[2], r[3]);
    float4 o1 = make_float4(r[4], r[5], r[6], r[7]);
    *reinterpret_cast<float4*>(outf + (size_t)d * D + c16 * 8) = o0;
    *reinterpret_cast<float4*>(outf + (size_t)d * D + c16 * 8 + 4) = o1;
  }
}

// ---------------- launch ----------------

extern "C" void kernel_launch(void* const* d_in, const int* in_sizes, int n_in,
                              void* d_out, int out_size, void* d_ws, size_t ws_size,
                              hipStream_t stream) {
  const float* x = (const float*)d_in[0];
  const int* esrc = (const int*)d_in[1];
  const int* edst = (const int*)d_in[2];
  const float* W0 = (const float*)d_in[3];
  const float* b0 = (const float*)d_in[4];
  const float* W1 = (const float*)d_in[5];
  const float* b1 = (const float*)d_in[6];
  const float* W2 = (const float*)d_in[7];
  const float* b2 = (const float*)d_in[8];
  const float* g0 = (const float*)d_in[9];
  const float* be0 = (const float*)d_in[10];
  const float* m0 = (const float*)d_in[11];
  const float* v0 = (const float*)d_in[12];
  const float* g1 = (const float*)d_in[13];
  const float* be1 = (const float*)d_in[14];
  const float* m1 = (const float*)d_in[15];
  const float* v1 = (const float*)d_in[16];
  const int N = in_sizes[0] / D;
  const int E = in_sizes[1];

  const int BPC = (((N + NCH - 1) / NCH) + 1) & ~1;        // even bins/chunk (<= 12544)
  const int S = (((E + NSL - 1) / NSL) + 3) & ~3;          // 4-aligned slice size

  char* p = (char*)d_ws;
  auto carve = [&](size_t bytes) {
    char* r = p;
    p += (bytes + 255) & ~(size_t)255;
    return (void*)r;
  };
  uint* hs16 = (uint*)carve((size_t)N * 64 * 4);           // GEMM out / SpMM in (f16 packed)
  ushort* Wt = (ushort*)carve((size_t)3 * D * D * 2);
  float* CA = (float*)carve((size_t)3 * D * 4);
  float* CB = (float*)carve((size_t)3 * D * 4);
  float* ns = (float*)carve((size_t)N * 4);
  float* nd = (float*)carve((size_t)N * 4);
  uint* partial_d = (uint*)carve((size_t)NCH * NSL * PBINS * 4);
  uint* partial_s = (uint*)carve((size_t)NCH * NSL * PBINS * 4);
  ushort* rank16 = (ushort*)carve((size_t)E * 2);
  int* totd = (int*)carve((size_t)N * 4);
  int* rofs = (int*)carve((size_t)(N + 1) * 4);
  const int nch = (N + 1023) / 1024;
  int* csum = (int*)carve((size_t)nch * 4);
  int* csr = (int*)carve((size_t)E * 4);
  uint* bufA = (uint*)d_out;  // GEMM input ping buffer lives in d_out (fully rewritten)

  k_prep<<<193, 256, 0, stream>>>(W0, W1, W2, b0, b1, b2, g0, be0, m0, v0, g1, be1, m1, v1,
                                  Wt, CA, CB);
  k_hist<<<NCH * NSL, 256, 0, stream>>>(esrc, edst, partial_d, partial_s, rank16, E, N, BPC, S);
  k_reduce<<<((N + 1) / 2 + 255) / 256, 256, 0, stream>>>(partial_d, partial_s, totd, ns, nd,
                                                          N, BPC);
  k_scan_partial<<<nch, 256, 0, stream>>>(totd, csum, N);
  k_scan_serial<<<1, 1, 0, stream>>>(csum, nch, rofs, N);
  k_scan_final<<<nch, 256, 0, stream>>>(totd, csum, rofs, N);
  k_scatter2<<<(E + 255) / 256, 256, 0, stream>>>(esrc, edst, rank16, partial_d, rofs, csr,
                                                  E, BPC, S);
  k_x16<<<(N * 32 + 255) / 256, 256, 0, stream>>>(x, ns, bufA, N);

  const int gb = (N + 127) / 128;
  const int sb = (N + 15) / 16;
  // layer 0
  k_gemm16<<<gb, 256, 0, stream>>>((const ushort*)bufA, Wt, (ushort*)hs16, N);
  k_spmm16<<<sb, 256, 0, stream>>>(hs16, csr, rofs, nd, ns, CA, CB, nullptr, bufA, N, 0);
  // layer 1
  k_gemm16<<<gb, 256, 0, stream>>>((const ushort*)bufA, Wt + 16384, (ushort*)hs16, N);
  k_spmm16<<<sb, 256, 0, stream>>>(hs16, csr, rofs, nd, ns, CA + D, CB + D, nullptr, bufA, N, 0);
  // layer 2
  k_gemm16<<<gb, 256, 0, stream>>>((const ushort*)bufA, Wt + 32768, (ushort*)hs16, N);
  k_spmm16<<<sb, 256, 0, stream>>>(hs16, csr, rofs, nd, ns, CA + 2 * D, CB + 2 * D,
                                   (float*)d_out, nullptr, N, 1);
}

// Round 9
// 285.606 us; speedup vs baseline: 9.6032x; 1.0333x over previous
//
#include <hip/hip_runtime.h>
#include <hip/hip_fp16.h>
#include <math.h>

#define D 128
#define NSL 32          // edge slices
#define PBU 25088       // packed u8 counters (uints) -> supports N <= 100352

typedef _Float16 half8 __attribute__((ext_vector_type(8)));
typedef float f32x4 __attribute__((ext_vector_type(4)));

__device__ inline uint pack_f16x2(float a, float b) {
  __half2 h = __floats2half2_rn(a, b);
  return *reinterpret_cast<uint*>(&h);
}
__device__ inline float2 unpack_f16x2(uint p) {
  __half2 h = *reinterpret_cast<__half2*>(&p);
  return __half22float2(h);
}
__device__ inline uint mdiv40(uint x, uint M) {  // x / d with M = ceil(2^40/d)
  return (uint)(((unsigned long long)x * M) >> 40);
}

// ---------------- dst histogram: whole node range in LDS as packed u8, rank record ----------

__global__ __launch_bounds__(1024) void k_histd(const int* __restrict__ edst,
                                                uint* __restrict__ pd,
                                                uchar* __restrict__ rank8,
                                                int E, int SB) {
  __shared__ uint h[PBU];   // ~98 KB static LDS (gfx950 allows >64KB)
  const int t = threadIdx.x, sl = blockIdx.x;
  for (int j = t; j < PBU; j += 1024) h[j] = 0u;
  __syncthreads();
  const int i0 = sl * SB, i1 = min(i0 + SB, E);
  for (int i = i0 + t; i < i1; i += 1024) {
    const int d = edst[i];
    const uint sh = (uint)(d & 3) * 8u;
    const uint old = atomicAdd(&h[d >> 2], 1u << sh);
    rank8[i] = (uchar)((old >> sh) & 0xffu);
  }
  __syncthreads();
  uint* p = pd + (size_t)sl * PBU;
  for (int j = t; j < PBU; j += 1024) p[j] = h[j];
}

// ---------------- src histogram: counts only ----------------

__global__ __launch_bounds__(1024) void k_hists(const int* __restrict__ esrc,
                                                uint* __restrict__ ps,
                                                int E, int SB) {
  __shared__ uint h[PBU];
  const int t = threadIdx.x, sl = blockIdx.x;
  for (int j = t; j < PBU; j += 1024) h[j] = 0u;
  __syncthreads();
  const int i0 = sl * SB, i1 = min(i0 + SB, E);
  for (int i = i0 + t; i < i1; i += 1024) {
    const int s = esrc[i];
    atomicAdd(&h[s >> 2], 1u << ((uint)(s & 3) * 8u));
  }
  __syncthreads();
  uint* p = ps + (size_t)sl * PBU;
  for (int j = t; j < PBU; j += 1024) p[j] = h[j];
}

// ------ reduce: totals + norms + in-place u8 slice-prefix for pd (deg<=255 assumed) ------

__global__ __launch_bounds__(256) void k_reduceN(uint* __restrict__ pd,
                                                 const uint* __restrict__ ps,
                                                 int* __restrict__ totd,
                                                 float* __restrict__ ns,
                                                 float* __restrict__ nd, int N) {
  const int j = blockIdx.x * 256 + threadIdx.x;  // packed uint index (4 nodes)
  const int n0 = j * 4;
  if (n0 >= N) return;
  uint r0 = 0, r1 = 0, r2 = 0, r3 = 0;
  uint s0 = 0, s1 = 0, s2 = 0, s3 = 0;
#pragma unroll
  for (int sl = 0; sl < NSL; ++sl) {
    const uint v = pd[(size_t)sl * PBU + j];
    pd[(size_t)sl * PBU + j] = r0 | (r1 << 8) | (r2 << 16) | (r3 << 24);
    r0 += v & 0xffu; r1 += (v >> 8) & 0xffu; r2 += (v >> 16) & 0xffu; r3 += (v >> 24) & 0xffu;
    const uint w = ps[(size_t)sl * PBU + j];
    s0 += w & 0xffu; s1 += (w >> 8) & 0xffu; s2 += (w >> 16) & 0xffu; s3 += (w >> 24) & 0xffu;
  }
  const uint rr[4] = {r0, r1, r2, r3};
  const uint ss[4] = {s0, s1, s2, s3};
#pragma unroll
  for (int k = 0; k < 4; ++k) {
    if (n0 + k < N) {
      totd[n0 + k] = (int)rr[k];
      nd[n0 + k] = rsqrtf((float)max(rr[k], 1u));
      ns[n0 + k] = rsqrtf((float)max(ss[k], 1u));
    }
  }
}

// ---------------- rofs scan over totd ----------------

__global__ __launch_bounds__(256) void k_scan_partial(const int* __restrict__ totd,
                                                      int* __restrict__ csum, int n) {
  __shared__ int sd[256];
  const int b = blockIdx.x, t = threadIdx.x;
  const int base = b * 1024 + t * 4;
  int s = 0;
#pragma unroll
  for (int i = 0; i < 4; ++i) { int idx = base + i; if (idx < n) s += totd[idx]; }
  sd[t] = s; __syncthreads();
  for (int off = 128; off > 0; off >>= 1) {
    if (t < off) sd[t] += sd[t + off];
    __syncthreads();
  }
  if (t == 0) csum[b] = sd[0];
}

__global__ void k_scan_serial(int* __restrict__ csum, int nch,
                              int* __restrict__ rofs, int n) {
  if (blockIdx.x == 0 && threadIdx.x == 0) {
    int run = 0;
    for (int b = 0; b < nch; ++b) { int v = csum[b]; csum[b] = run; run += v; }
    rofs[n] = run;
  }
}

__global__ __launch_bounds__(256) void k_scan_final(const int* __restrict__ totd,
                                                    const int* __restrict__ csum,
                                                    int* __restrict__ rofs, int n) {
  __shared__ int sd[256];
  const int b = blockIdx.x, t = threadIdx.x;
  const int base = b * 1024 + t * 4;
  int v[4]; int s = 0;
#pragma unroll
  for (int i = 0; i < 4; ++i) { v[i] = (base + i < n) ? totd[base + i] : 0; s += v[i]; }
  sd[t] = s; __syncthreads();
  for (int off = 1; off < 256; off <<= 1) {
    int x = (t >= off) ? sd[t - off] : 0;
    __syncthreads();
    sd[t] += x;
    __syncthreads();
  }
  int o = sd[t] - s + csum[b];
#pragma unroll
  for (int i = 0; i < 4; ++i) {
    if (base + i < n) { rofs[base + i] = o; o += v[i]; }
  }
}

// ---------------- atomic-free scatter ----------------

__global__ void k_scatter2(const int* __restrict__ esrc, const int* __restrict__ edst,
                           const uchar* __restrict__ rank8,
                           const uint* __restrict__ pd,
                           const int* __restrict__ rofs, int* __restrict__ csr,
                           int E, uint Msb) {
  const int i = blockIdx.x * 256 + threadIdx.x;
  if (i >= E) return;
  const int d = edst[i];
  const uint sl = mdiv40((uint)i, Msb);
  const uint pk = pd[(size_t)sl * PBU + (d >> 2)];
  const uint pfx = (pk >> ((uint)(d & 3) * 8u)) & 0xffu;
  csr[rofs[d] + (int)pfx + (int)rank8[i]] = esrc[i];
}

// ---------------- prep: Wt[l][n][k] = f16(W_l[k][n]); CA/CB fold bias+BN ----------------

__global__ void k_prep(const float* __restrict__ W0, const float* __restrict__ W1,
                       const float* __restrict__ W2,
                       const float* __restrict__ b0, const float* __restrict__ b1,
                       const float* __restrict__ b2,
                       const float* __restrict__ g0, const float* __restrict__ be0,
                       const float* __restrict__ mu0, const float* __restrict__ vr0,
                       const float* __restrict__ g1, const float* __restrict__ be1,
                       const float* __restrict__ mu1, const float* __restrict__ vr1,
                       ushort* __restrict__ Wt, float* __restrict__ CA,
                       float* __restrict__ CB) {
  int b = blockIdx.x;
  if (b < 192) {
    int li = b * 256 + threadIdx.x;
    int l = li >> 14;
    int i = li & 16383;
    int n = i >> 7, k = i & 127;
    const float* W = (l == 0) ? W0 : ((l == 1) ? W1 : W2);
    Wt[li] = __half_as_ushort(__float2half_rn(W[k * D + n]));
  } else if (threadIdx.x < D) {
    int c = threadIdx.x;
    float A0 = g0[c] * rsqrtf(vr0[c] + 1e-5f);
    CA[c] = A0;
    CB[c] = (b0[c] - mu0[c]) * A0 + be0[c];
    float A1 = g1[c] * rsqrtf(vr1[c] + 1e-5f);
    CA[D + c] = A1;
    CB[D + c] = (b1[c] - mu1[c]) * A1 + be1[c];
    CA[2 * D + c] = 1.f;
    CB[2 * D + c] = b2[c];
  }
}

// ---------------- MFMA GEMM, f32 input variant (layer 0): reads x, scales by ns ----------

__global__ __launch_bounds__(256) void k_gemm32(const float* __restrict__ X,
                                                const ushort* __restrict__ Wt,
                                                const float* __restrict__ ns,
                                                ushort* __restrict__ out, int M) {
  const int lane = threadIdx.x & 63;
  const int wv = threadIdx.x >> 6;
  const int m0 = (blockIdx.x * 4 + wv) * 32;
  if (m0 >= M) return;
  const int lr = lane & 15;
  const int kg = (lane >> 4) * 8;

  half8 hf[2][4];
  const half8 hz = {};
#pragma unroll
  for (int mt = 0; mt < 2; ++mt) {
    const int row = m0 + mt * 16 + lr;
    if (row < M) {
      const float s = ns[row];
#pragma unroll
      for (int kt = 0; kt < 4; ++kt) {
        const float4 a = *reinterpret_cast<const float4*>(X + (size_t)row * D + kt * 32 + kg);
        const float4 b = *reinterpret_cast<const float4*>(X + (size_t)row * D + kt * 32 + kg + 4);
        half8 hv;
        hv[0] = (_Float16)(a.x * s); hv[1] = (_Float16)(a.y * s);
        hv[2] = (_Float16)(a.z * s); hv[3] = (_Float16)(a.w * s);
        hv[4] = (_Float16)(b.x * s); hv[5] = (_Float16)(b.y * s);
        hv[6] = (_Float16)(b.z * s); hv[7] = (_Float16)(b.w * s);
        hf[mt][kt] = hv;
      }
    } else {
#pragma unroll
      for (int kt = 0; kt < 4; ++kt) hf[mt][kt] = hz;
    }
  }

  f32x4 acc[8][2];
#pragma unroll
  for (int nt = 0; nt < 8; ++nt) { acc[nt][0] = (f32x4)(0.f); acc[nt][1] = (f32x4)(0.f); }

#pragma unroll
  for (int nt = 0; nt < 8; ++nt) {
    const ushort* wb = Wt + (size_t)(nt * 16 + lr) * D + kg;
#pragma unroll
    for (int kt = 0; kt < 4; ++kt) {
      half8 wf = *reinterpret_cast<const half8*>(wb + kt * 32);
      acc[nt][0] = __builtin_amdgcn_mfma_f32_16x16x32_f16(wf, hf[0][kt], acc[nt][0], 0, 0, 0);
      acc[nt][1] = __builtin_amdgcn_mfma_f32_16x16x32_f16(wf, hf[1][kt], acc[nt][1], 0, 0, 0);
    }
  }

  const int mo = lane & 15;
  const int no = (lane >> 4) * 4;
#pragma unroll
  for (int mt = 0; mt < 2; ++mt) {
    const int row = m0 + mt * 16 + mo;
    if (row < M) {
#pragma unroll
      for (int nt = 0; nt < 8; ++nt) {
        uint2 u;
        u.x = pack_f16x2(acc[nt][mt][0], acc[nt][mt][1]);
        u.y = pack_f16x2(acc[nt][mt][2], acc[nt][mt][3]);
        *reinterpret_cast<uint2*>(out + (size_t)row * D + nt * 16 + no) = u;
      }
    }
  }
}

// ---------------- MFMA GEMM (f16 in, f16 out) ----------------

__global__ __launch_bounds__(256) void k_gemm16(const ushort* __restrict__ A,
                                                const ushort* __restrict__ Wt,
                                                ushort* __restrict__ out, int M) {
  const int lane = threadIdx.x & 63;
  const int wv = threadIdx.x >> 6;
  const int m0 = (blockIdx.x * 4 + wv) * 32;
  if (m0 >= M) return;
  const int lr = lane & 15;
  const int kg = (lane >> 4) * 8;

  half8 hf[2][4];
  const half8 hz = {};
#pragma unroll
  for (int mt = 0; mt < 2; ++mt) {
    const int row = m0 + mt * 16 + lr;
    const bool ok = row < M;
#pragma unroll
    for (int kt = 0; kt < 4; ++kt)
      hf[mt][kt] = ok ? *reinterpret_cast<const half8*>(A + (size_t)row * D + kt * 32 + kg)
                      : hz;
  }

  f32x4 acc[8][2];
#pragma unroll
  for (int nt = 0; nt < 8; ++nt) { acc[nt][0] = (f32x4)(0.f); acc[nt][1] = (f32x4)(0.f); }

#pragma unroll
  for (int nt = 0; nt < 8; ++nt) {
    const ushort* wb = Wt + (size_t)(nt * 16 + lr) * D + kg;
#pragma unroll
    for (int kt = 0; kt < 4; ++kt) {
      half8 wf = *reinterpret_cast<const half8*>(wb + kt * 32);
      acc[nt][0] = __builtin_amdgcn_mfma_f32_16x16x32_f16(wf, hf[0][kt], acc[nt][0], 0, 0, 0);
      acc[nt][1] = __builtin_amdgcn_mfma_f32_16x16x32_f16(wf, hf[1][kt], acc[nt][1], 0, 0, 0);
    }
  }

  const int mo = lane & 15;
  const int no = (lane >> 4) * 4;
#pragma unroll
  for (int mt = 0; mt < 2; ++mt) {
    const int row = m0 + mt * 16 + mo;
    if (row < M) {
#pragma unroll
      for (int nt = 0; nt < 8; ++nt) {
        uint2 u;
        u.x = pack_f16x2(acc[nt][mt][0], acc[nt][mt][1]);
        u.y = pack_f16x2(acc[nt][mt][2], acc[nt][mt][3]);
        *reinterpret_cast<uint2*>(out + (size_t)row * D + nt * 16 + no) = u;
      }
    }
  }
}

// ---------------- SpMM: 16-lane group per dst row, 8-deep clamped gather unroll ----------

__global__ __launch_bounds__(256) void k_spmm16(const uint* __restrict__ hs,
                                                const int* __restrict__ csr,
                                                const int* __restrict__ rofs,
                                                const float* __restrict__ nd,
                                                const float* __restrict__ ns,
                                                const float* __restrict__ CA,
                                                const float* __restrict__ CB,
                                                float* __restrict__ outf,
                                                uint* __restrict__ hnext,
                                                int N, int last) {
  const int t = threadIdx.x;
  const int lane = t & 63;
  const int c16 = lane & 15;       // col group: this lane owns cols c16*8..c16*8+7
  const int gb = lane & ~15;       // group's base lane within the wave
  const int d = blockIdx.x * 16 + (t >> 4);
  if (d >= N) return;              // uniform per 16-lane group; shfl stays intra-group
  const int beg = rofs[d], end = rofs[d + 1];

  float acc[8];
#pragma unroll
  for (int j = 0; j < 8; ++j) acc[j] = 0.f;

  for (int base = beg; base < end; base += 16) {
    const int len = min(16, end - base);
    const int idx = csr[min(base + c16, end - 1)];
    for (int j = 0; j < len; j += 8) {
      // 8 clamped slots: tail gathers duplicate the last edge (L1 hit) with
      // weight 0 so the sum is exact; flat control flow -> 8 gathers in flight.
      int sl_[8]; float w[8];
#pragma unroll
      for (int q = 0; q < 8; ++q) {
        const int lq = min(j + q, len - 1);
        sl_[q] = __shfl(idx, gb + lq);
        w[q] = (j + q < len) ? 1.f : 0.f;
      }
      uint4 v[8];
#pragma unroll
      for (int q = 0; q < 8; ++q)
        v[q] = *reinterpret_cast<const uint4*>(hs + (size_t)sl_[q] * 64 + c16 * 4);
#pragma unroll
      for (int q = 0; q < 8; ++q) {
#pragma unroll
        for (int p2 = 0; p2 < 4; ++p2) {
          const float2 a = unpack_f16x2((&v[q].x)[p2]);
          acc[p2 * 2]     = fmaf(a.x, w[q], acc[p2 * 2]);
          acc[p2 * 2 + 1] = fmaf(a.y, w[q], acc[p2 * 2 + 1]);
        }
      }
    }
  }

  const float ndv = nd[d];
  const float4 ca0 = *reinterpret_cast<const float4*>(CA + c16 * 8);
  const float4 ca1 = *reinterpret_cast<const float4*>(CA + c16 * 8 + 4);
  const float4 cb0 = *reinterpret_cast<const float4*>(CB + c16 * 8);
  const float4 cb1 = *reinterpret_cast<const float4*>(CB + c16 * 8 + 4);
  float r[8];
  r[0] = acc[0] * ndv * ca0.x + cb0.x;
  r[1] = acc[1] * ndv * ca0.y + cb0.y;
  r[2] = acc[2] * ndv * ca0.z + cb0.z;
  r[3] = acc[3] * ndv * ca0.w + cb0.w;
  r[4] = acc[4] * ndv * ca1.x + cb1.x;
  r[5] = acc[5] * ndv * ca1.y + cb1.y;
  r[6] = acc[6] * ndv * ca1.z + cb1.z;
  r[7] = acc[7] * ndv * ca1.w + cb1.w;
  if (!last) {
    const float s = ns[d];
#pragma unroll
    for (int j = 0; j < 8; ++j) r[j] = fmaxf(r[j], 0.f) * s;
    uint4 u;
    u.x = pack_f16x2(r[0], r[1]);
    u.y = pack_f16x2(r[2], r[3]);
    u.z = pack_f16x2(r[4], r[5]);
    u.w = pack_f16x2(r[6], r[7]);
    *reinterpret_cast<uint4*>(hnext + (size_t)d * 64 + c16 * 4) = u;
  } else {
    float4 o0 = make_float4(r[0], r[1], r[2], r[3]);
    float4 o1 = make_float4(r[4], r[5], r[6], r[7]);
    *reinterpret_cast<float4*>(outf + (size_t)d * D + c16 * 8) = o0;
    *reinterpret_cast<float4*>(outf + (size_t)d * D + c16 * 8 + 4) = o1;
  }
}

// ---------------- launch ----------------

extern "C" void kernel_launch(void* const* d_in, const int* in_sizes, int n_in,
                              void* d_out, int out_size, void* d_ws, size_t ws_size,
                              hipStream_t stream) {
  const float* x = (const float*)d_in[0];
  const int* esrc = (const int*)d_in[1];
  const int* edst = (const int*)d_in[2];
  const float* W0 = (const float*)d_in[3];
  const float* b0 = (const float*)d_in[4];
  const float* W1 = (const float*)d_in[5];
  const float* b1 = (const float*)d_in[6];
  const float* W2 = (const float*)d_in[7];
  const float* b2 = (const float*)d_in[8];
  const float* g0 = (const float*)d_in[9];
  const float* be0 = (const float*)d_in[10];
  const float* m0 = (const float*)d_in[11];
  const float* v0 = (const float*)d_in[12];
  const float* g1 = (const float*)d_in[13];
  const float* be1 = (const float*)d_in[14];
  const float* m1 = (const float*)d_in[15];
  const float* v1 = (const float*)d_in[16];
  const int N = in_sizes[0] / D;
  const int E = in_sizes[1];

  const int SB = (E + NSL - 1) / NSL;
  const uint Msb = (uint)(((1ULL << 40) + (unsigned long long)SB - 1) / (unsigned long long)SB);

  char* p = (char*)d_ws;
  auto carve = [&](size_t bytes) {
    char* r = p;
    p += (bytes + 255) & ~(size_t)255;
    return (void*)r;
  };
  uint* hs16 = (uint*)carve((size_t)N * 64 * 4);           // GEMM out / SpMM in (f16 packed)
  ushort* Wt = (ushort*)carve((size_t)3 * D * D * 2);
  float* CA = (float*)carve((size_t)3 * D * 4);
  float* CB = (float*)carve((size_t)3 * D * 4);
  float* ns = (float*)carve((size_t)N * 4);
  float* nd = (float*)carve((size_t)N * 4);
  uint* pd = (uint*)carve((size_t)NSL * PBU * 4);
  uint* ps = (uint*)carve((size_t)NSL * PBU * 4);
  uchar* rank8 = (uchar*)carve((size_t)E);
  int* totd = (int*)carve((size_t)N * 4);
  int* rofs = (int*)carve((size_t)(N + 1) * 4);
  const int nch = (N + 1023) / 1024;
  int* csum = (int*)carve((size_t)nch * 4);
  int* csr = (int*)carve((size_t)E * 4);
  uint* bufA = (uint*)d_out;  // inter-layer f16 ping buffer lives in d_out (fully rewritten)

  k_prep<<<193, 256, 0, stream>>>(W0, W1, W2, b0, b1, b2, g0, be0, m0, v0, g1, be1, m1, v1,
                                  Wt, CA, CB);
  k_histd<<<NSL, 1024, 0, stream>>>(edst, pd, rank8, E, SB);
  k_hists<<<NSL, 1024, 0, stream>>>(esrc, ps, E, SB);
  k_reduceN<<<(N / 4 + 256) / 256, 256, 0, stream>>>(pd, ps, totd, ns, nd, N);
  k_scan_partial<<<nch, 256, 0, stream>>>(totd, csum, N);
  k_scan_serial<<<1, 1, 0, stream>>>(csum, nch, rofs, N);
  k_scan_final<<<nch, 256, 0, stream>>>(totd, csum, rofs, N);
  k_scatter2<<<(E + 255) / 256, 256, 0, stream>>>(esrc, edst, rank8, pd, rofs, csr, E, Msb);

  const int gb = (N + 127) / 128;
  const int sb = (N + 15) / 16;
  // layer 0 (reads x f32 directly, ns folded in)
  k_gemm32<<<gb, 256, 0, stream>>>(x, Wt, ns, (ushort*)hs16, N);
  k_spmm16<<<sb, 256, 0, stream>>>(hs16, csr, rofs, nd, ns, CA, CB, nullptr, bufA, N, 0);
  // layer 1
  k_gemm16<<<gb, 256, 0, stream>>>((const ushort*)bufA, Wt + 16384, (ushort*)hs16, N);
  k_spmm16<<<sb, 256, 0, stream>>>(hs16, csr, rofs, nd, ns, CA + D, CB + D, nullptr, bufA, N, 0);
  // layer 2
  k_gemm16<<<gb, 256, 0, stream>>>((const ushort*)bufA, Wt + 32768, (ushort*)hs16, N);
  k_spmm16<<<sb, 256, 0, stream>>>(hs16, csr, rofs, nd, ns, CA + 2 * D, CB + 2 * D,
                                   (float*)d_out, nullptr, N, 1);
}

// Round 10
// 267.573 us; speedup vs baseline: 10.2504x; 1.0674x over previous
//
#include <hip/hip_runtime.h>
#include <hip/hip_fp16.h>
#include <math.h>

#define D 128
#define NSL 32          // edge slices
#define PBU 25088       // packed u8 counters (uints) -> supports N <= 100352

typedef _Float16 half8 __attribute__((ext_vector_type(8)));
typedef float f32x4 __attribute__((ext_vector_type(4)));

__device__ inline uint pack_f16x2(float a, float b) {
  __half2 h = __floats2half2_rn(a, b);
  return *reinterpret_cast<uint*>(&h);
}
__device__ inline float2 unpack_f16x2(uint p) {
  __half2 h = *reinterpret_cast<__half2*>(&p);
  return __half22float2(h);
}
__device__ inline uint mdiv40(uint x, uint M) {  // x / d with M = ceil(2^40/d)
  return (uint)(((unsigned long long)x * M) >> 40);
}

// ---------------- build1: fused {dst-hist+rank, src-hist, Wt transpose, CA/CB} ----------
// blocks 0..31: dst histogram slice; 32..63: src histogram slice; 64..111: Wt; 112: CA/CB.

__global__ __launch_bounds__(1024) void k_build1(const int* __restrict__ esrc,
                                                 const int* __restrict__ edst,
                                                 const float* __restrict__ W0,
                                                 const float* __restrict__ W1,
                                                 const float* __restrict__ W2,
                                                 const float* __restrict__ b0,
                                                 const float* __restrict__ b1,
                                                 const float* __restrict__ b2,
                                                 const float* __restrict__ g0,
                                                 const float* __restrict__ be0,
                                                 const float* __restrict__ mu0,
                                                 const float* __restrict__ vr0,
                                                 const float* __restrict__ g1,
                                                 const float* __restrict__ be1,
                                                 const float* __restrict__ mu1,
                                                 const float* __restrict__ vr1,
                                                 uint* __restrict__ pd,
                                                 uint* __restrict__ ps,
                                                 uchar* __restrict__ rank8,
                                                 ushort* __restrict__ Wt,
                                                 float* __restrict__ CA,
                                                 float* __restrict__ CB,
                                                 int E, int SB) {
  __shared__ uint h[PBU];   // ~98 KB static LDS (hist blocks only)
  const int b = blockIdx.x;
  const int t = threadIdx.x;
  if (b < 32) {             // ---- dst histogram + rank record
    for (int j = t; j < PBU; j += 1024) h[j] = 0u;
    __syncthreads();
    const int i0 = b * SB, i1 = min(i0 + SB, E);
    for (int i = i0 + t; i < i1; i += 1024) {
      const int d = edst[i];
      const uint sh = (uint)(d & 3) * 8u;
      const uint old = atomicAdd(&h[d >> 2], 1u << sh);
      rank8[i] = (uchar)((old >> sh) & 0xffu);
    }
    __syncthreads();
    uint* p = pd + (size_t)b * PBU;
    for (int j = t; j < PBU; j += 1024) p[j] = h[j];
  } else if (b < 64) {      // ---- src histogram (counts only)
    const int sl = b - 32;
    for (int j = t; j < PBU; j += 1024) h[j] = 0u;
    __syncthreads();
    const int i0 = sl * SB, i1 = min(i0 + SB, E);
    for (int i = i0 + t; i < i1; i += 1024) {
      const int s = esrc[i];
      atomicAdd(&h[s >> 2], 1u << ((uint)(s & 3) * 8u));
    }
    __syncthreads();
    uint* p = ps + (size_t)sl * PBU;
    for (int j = t; j < PBU; j += 1024) p[j] = h[j];
  } else if (b < 112) {     // ---- Wt[l][n][k] = f16(W_l[k][n])
    const int li = (b - 64) * 1024 + t;   // 0..49151
    const int l = li >> 14;
    const int i = li & 16383;
    const int n = i >> 7, k = i & 127;
    const float* W = (l == 0) ? W0 : ((l == 1) ? W1 : W2);
    Wt[li] = __half_as_ushort(__float2half_rn(W[k * D + n]));
  } else if (t < D) {       // ---- CA/CB fold bias+BN
    const int c = t;
    float A0 = g0[c] * rsqrtf(vr0[c] + 1e-5f);
    CA[c] = A0;
    CB[c] = (b0[c] - mu0[c]) * A0 + be0[c];
    float A1 = g1[c] * rsqrtf(vr1[c] + 1e-5f);
    CA[D + c] = A1;
    CB[D + c] = (b1[c] - mu1[c]) * A1 + be1[c];
    CA[2 * D + c] = 1.f;
    CB[2 * D + c] = b2[c];
  }
}

// ------ build2: fused {reduceN (totals/norms/in-place u8 prefix) + block partial sum} ----

__global__ __launch_bounds__(256) void k_build2(uint* __restrict__ pd,
                                                const uint* __restrict__ ps,
                                                int* __restrict__ totd,
                                                float* __restrict__ ns,
                                                float* __restrict__ nd,
                                                int* __restrict__ csum, int N) {
  __shared__ int sd[256];
  const int t = threadIdx.x;
  const int j = blockIdx.x * 256 + t;    // packed uint index (4 nodes)
  const int n0 = j * 4;
  uint r0 = 0, r1 = 0, r2 = 0, r3 = 0;
  uint s0 = 0, s1 = 0, s2 = 0, s3 = 0;
#pragma unroll
  for (int sl = 0; sl < NSL; ++sl) {
    const uint v = pd[(size_t)sl * PBU + j];
    pd[(size_t)sl * PBU + j] = r0 | (r1 << 8) | (r2 << 16) | (r3 << 24);
    r0 += v & 0xffu; r1 += (v >> 8) & 0xffu; r2 += (v >> 16) & 0xffu; r3 += (v >> 24) & 0xffu;
    const uint w = ps[(size_t)sl * PBU + j];
    s0 += w & 0xffu; s1 += (w >> 8) & 0xffu; s2 += (w >> 16) & 0xffu; s3 += (w >> 24) & 0xffu;
  }
  const uint rr[4] = {r0, r1, r2, r3};
  const uint ss[4] = {s0, s1, s2, s3};
  int tot = 0;
#pragma unroll
  for (int k = 0; k < 4; ++k) {
    if (n0 + k < N) {
      totd[n0 + k] = (int)rr[k];
      nd[n0 + k] = rsqrtf((float)max(rr[k], 1u));
      ns[n0 + k] = rsqrtf((float)max(ss[k], 1u));
      tot += (int)rr[k];
    }
  }
  sd[t] = tot; __syncthreads();
  for (int off = 128; off > 0; off >>= 1) {
    if (t < off) sd[t] += sd[t + off];
    __syncthreads();
  }
  if (t == 0) csum[blockIdx.x] = sd[0];
}

// ---------------- serial chunk scan + final per-node scan ----------------

__global__ void k_scan_serial(int* __restrict__ csum, int nch,
                              int* __restrict__ rofs, int n) {
  if (blockIdx.x == 0 && threadIdx.x == 0) {
    int run = 0;
    for (int b = 0; b < nch; ++b) { int v = csum[b]; csum[b] = run; run += v; }
    rofs[n] = run;
  }
}

__global__ __launch_bounds__(256) void k_scan_final(const int* __restrict__ totd,
                                                    const int* __restrict__ csum,
                                                    int* __restrict__ rofs, int n) {
  __shared__ int sd[256];
  const int b = blockIdx.x, t = threadIdx.x;
  const int base = b * 1024 + t * 4;
  int v[4]; int s = 0;
#pragma unroll
  for (int i = 0; i < 4; ++i) { v[i] = (base + i < n) ? totd[base + i] : 0; s += v[i]; }
  sd[t] = s; __syncthreads();
  for (int off = 1; off < 256; off <<= 1) {
    int x = (t >= off) ? sd[t - off] : 0;
    __syncthreads();
    sd[t] += x;
    __syncthreads();
  }
  int o = sd[t] - s + csum[b];
#pragma unroll
  for (int i = 0; i < 4; ++i) {
    if (base + i < n) { rofs[base + i] = o; o += v[i]; }
  }
}

// ---------------- atomic-free scatter ----------------

__global__ void k_scatter2(const int* __restrict__ esrc, const int* __restrict__ edst,
                           const uchar* __restrict__ rank8,
                           const uint* __restrict__ pd,
                           const int* __restrict__ rofs, int* __restrict__ csr,
                           int E, uint Msb) {
  const int i = blockIdx.x * 256 + threadIdx.x;
  if (i >= E) return;
  const int d = edst[i];
  const uint sl = mdiv40((uint)i, Msb);
  const uint pk = pd[(size_t)sl * PBU + (d >> 2)];
  const uint pfx = (pk >> ((uint)(d & 3) * 8u)) & 0xffu;
  csr[rofs[d] + (int)pfx + (int)rank8[i]] = esrc[i];
}

// ---------------- MFMA GEMM, f32 input variant (layer 0): reads x, scales by ns ----------

__global__ __launch_bounds__(256) void k_gemm32(const float* __restrict__ X,
                                                const ushort* __restrict__ Wt,
                                                const float* __restrict__ ns,
                                                ushort* __restrict__ out, int M) {
  const int lane = threadIdx.x & 63;
  const int wv = threadIdx.x >> 6;
  const int m0 = (blockIdx.x * 4 + wv) * 32;
  if (m0 >= M) return;
  const int lr = lane & 15;
  const int kg = (lane >> 4) * 8;

  half8 hf[2][4];
  const half8 hz = {};
#pragma unroll
  for (int mt = 0; mt < 2; ++mt) {
    const int row = m0 + mt * 16 + lr;
    if (row < M) {
      const float s = ns[row];
#pragma unroll
      for (int kt = 0; kt < 4; ++kt) {
        const float4 a = *reinterpret_cast<const float4*>(X + (size_t)row * D + kt * 32 + kg);
        const float4 b = *reinterpret_cast<const float4*>(X + (size_t)row * D + kt * 32 + kg + 4);
        half8 hv;
        hv[0] = (_Float16)(a.x * s); hv[1] = (_Float16)(a.y * s);
        hv[2] = (_Float16)(a.z * s); hv[3] = (_Float16)(a.w * s);
        hv[4] = (_Float16)(b.x * s); hv[5] = (_Float16)(b.y * s);
        hv[6] = (_Float16)(b.z * s); hv[7] = (_Float16)(b.w * s);
        hf[mt][kt] = hv;
      }
    } else {
#pragma unroll
      for (int kt = 0; kt < 4; ++kt) hf[mt][kt] = hz;
    }
  }

  f32x4 acc[8][2];
#pragma unroll
  for (int nt = 0; nt < 8; ++nt) { acc[nt][0] = (f32x4)(0.f); acc[nt][1] = (f32x4)(0.f); }

#pragma unroll
  for (int nt = 0; nt < 8; ++nt) {
    const ushort* wb = Wt + (size_t)(nt * 16 + lr) * D + kg;
#pragma unroll
    for (int kt = 0; kt < 4; ++kt) {
      half8 wf = *reinterpret_cast<const half8*>(wb + kt * 32);
      acc[nt][0] = __builtin_amdgcn_mfma_f32_16x16x32_f16(wf, hf[0][kt], acc[nt][0], 0, 0, 0);
      acc[nt][1] = __builtin_amdgcn_mfma_f32_16x16x32_f16(wf, hf[1][kt], acc[nt][1], 0, 0, 0);
    }
  }

  const int mo = lane & 15;
  const int no = (lane >> 4) * 4;
#pragma unroll
  for (int mt = 0; mt < 2; ++mt) {
    const int row = m0 + mt * 16 + mo;
    if (row < M) {
#pragma unroll
      for (int nt = 0; nt < 8; ++nt) {
        uint2 u;
        u.x = pack_f16x2(acc[nt][mt][0], acc[nt][mt][1]);
        u.y = pack_f16x2(acc[nt][mt][2], acc[nt][mt][3]);
        *reinterpret_cast<uint2*>(out + (size_t)row * D + nt * 16 + no) = u;
      }
    }
  }
}

// ---------------- MFMA GEMM (f16 in, f16 out) ----------------

__global__ __launch_bounds__(256) void k_gemm16(const ushort* __restrict__ A,
                                                const ushort* __restrict__ Wt,
                                                ushort* __restrict__ out, int M) {
  const int lane = threadIdx.x & 63;
  const int wv = threadIdx.x >> 6;
  const int m0 = (blockIdx.x * 4 + wv) * 32;
  if (m0 >= M) return;
  const int lr = lane & 15;
  const int kg = (lane >> 4) * 8;

  half8 hf[2][4];
  const half8 hz = {};
#pragma unroll
  for (int mt = 0; mt < 2; ++mt) {
    const int row = m0 + mt * 16 + lr;
    const bool ok = row < M;
#pragma unroll
    for (int kt = 0; kt < 4; ++kt)
      hf[mt][kt] = ok ? *reinterpret_cast<const half8*>(A + (size_t)row * D + kt * 32 + kg)
                      : hz;
  }

  f32x4 acc[8][2];
#pragma unroll
  for (int nt = 0; nt < 8; ++nt) { acc[nt][0] = (f32x4)(0.f); acc[nt][1] = (f32x4)(0.f); }

#pragma unroll
  for (int nt = 0; nt < 8; ++nt) {
    const ushort* wb = Wt + (size_t)(nt * 16 + lr) * D + kg;
#pragma unroll
    for (int kt = 0; kt < 4; ++kt) {
      half8 wf = *reinterpret_cast<const half8*>(wb + kt * 32);
      acc[nt][0] = __builtin_amdgcn_mfma_f32_16x16x32_f16(wf, hf[0][kt], acc[nt][0], 0, 0, 0);
      acc[nt][1] = __builtin_amdgcn_mfma_f32_16x16x32_f16(wf, hf[1][kt], acc[nt][1], 0, 0, 0);
    }
  }

  const int mo = lane & 15;
  const int no = (lane >> 4) * 4;
#pragma unroll
  for (int mt = 0; mt < 2; ++mt) {
    const int row = m0 + mt * 16 + mo;
    if (row < M) {
#pragma unroll
      for (int nt = 0; nt < 8; ++nt) {
        uint2 u;
        u.x = pack_f16x2(acc[nt][mt][0], acc[nt][mt][1]);
        u.y = pack_f16x2(acc[nt][mt][2], acc[nt][mt][3]);
        *reinterpret_cast<uint2*>(out + (size_t)row * D + nt * 16 + no) = u;
      }
    }
  }
}

// ---------------- SpMM: 16-lane group per dst row (4 rows/wave), 4-deep clamped gather ----

__global__ __launch_bounds__(256) void k_spmm16(const uint* __restrict__ hs,
                                                const int* __restrict__ csr,
                                                const int* __restrict__ rofs,
                                                const float* __restrict__ nd,
                                                const float* __restrict__ ns,
                                                const float* __restrict__ CA,
                                                const float* __restrict__ CB,
                                                float* __restrict__ outf,
                                                uint* __restrict__ hnext,
                                                int N, int last) {
  const int t = threadIdx.x;
  const int lane = t & 63;
  const int c16 = lane & 15;       // col group: this lane owns cols c16*8..c16*8+7
  const int gb = lane & ~15;       // group's base lane within the wave
  const int d = blockIdx.x * 16 + (t >> 4);
  if (d >= N) return;              // uniform per 16-lane group; shfl stays intra-group
  const int beg = rofs[d], end = rofs[d + 1];

  float acc[8];
#pragma unroll
  for (int j = 0; j < 8; ++j) acc[j] = 0.f;

  for (int base = beg; base < end; base += 16) {
    const int len = min(16, end - base);
    // 16-lane coalesced index load (clamped -> always defined for shfl)
    const int idx = csr[min(base + c16, end - 1)];
#pragma unroll 1
    for (int j = 0; j < len; j += 4) {
      // clamped source slots: tail gathers duplicate the last edge (L1 hit),
      // accumulation weighted 0 so the sum is exact; control flow stays flat.
      const int l1 = min(j + 1, len - 1), l2 = min(j + 2, len - 1), l3 = min(j + 3, len - 1);
      const int s0 = __shfl(idx, gb + j);
      const int s1 = __shfl(idx, gb + l1);
      const int s2 = __shfl(idx, gb + l2);
      const int s3 = __shfl(idx, gb + l3);
      const float w1 = (j + 1 < len) ? 1.f : 0.f;
      const float w2 = (j + 2 < len) ? 1.f : 0.f;
      const float w3 = (j + 3 < len) ? 1.f : 0.f;
      const uint4 v0 = *reinterpret_cast<const uint4*>(hs + (size_t)s0 * 64 + c16 * 4);
      const uint4 v1 = *reinterpret_cast<const uint4*>(hs + (size_t)s1 * 64 + c16 * 4);
      const uint4 v2 = *reinterpret_cast<const uint4*>(hs + (size_t)s2 * 64 + c16 * 4);
      const uint4 v3 = *reinterpret_cast<const uint4*>(hs + (size_t)s3 * 64 + c16 * 4);
#pragma unroll
      for (int q = 0; q < 4; ++q) {
        const uint u0 = (&v0.x)[q], u1 = (&v1.x)[q], u2 = (&v2.x)[q], u3 = (&v3.x)[q];
        const float2 a0 = unpack_f16x2(u0);
        const float2 a1 = unpack_f16x2(u1);
        const float2 a2 = unpack_f16x2(u2);
        const float2 a3 = unpack_f16x2(u3);
        acc[q * 2]     += a0.x;
        acc[q * 2 + 1] += a0.y;
        acc[q * 2]     = fmaf(a1.x, w1, acc[q * 2]);
        acc[q * 2 + 1] = fmaf(a1.y, w1, acc[q * 2 + 1]);
        acc[q * 2]     = fmaf(a2.x, w2, acc[q * 2]);
        acc[q * 2 + 1] = fmaf(a2.y, w2, acc[q * 2 + 1]);
        acc[q * 2]     = fmaf(a3.x, w3, acc[q * 2]);
        acc[q * 2 + 1] = fmaf(a3.y, w3, acc[q * 2 + 1]);
      }
    }
  }

  const float ndv = nd[d];
  const float4 ca0 = *reinterpret_cast<const float4*>(CA + c16 * 8);
  const float4 ca1 = *reinterpret_cast<const float4*>(CA + c16 * 8 + 4);
  const float4 cb0 = *reinterpret_cast<const float4*>(CB + c16 * 8);
  const float4 cb1 = *reinterpret_cast<const float4*>(CB + c16 * 8 + 4);
  float r[8];
  r[0] = acc[0] * ndv * ca0.x + cb0.x;
  r[1] = acc[1] * ndv * ca0.y + cb0.y;
  r[2] = acc[2] * ndv * ca0.z + cb0.z;
  r[3] = acc[3] * ndv * ca0.w + cb0.w;
  r[4] = acc[4] * ndv * ca1.x + cb1.x;
  r[5] = acc[5] * ndv * ca1.y + cb1.y;
  r[6] = acc[6] * ndv * ca1.z + cb1.z;
  r[7] = acc[7] * ndv * ca1.w + cb1.w;
  if (!last) {
    const float s = ns[d];
#pragma unroll
    for (int j = 0; j < 8; ++j) r[j] = fmaxf(r[j], 0.f) * s;
    uint4 u;
    u.x = pack_f16x2(r[0], r[1]);
    u.y = pack_f16x2(r[2], r[3]);
    u.z = pack_f16x2(r[4], r[5]);
    u.w = pack_f16x2(r[6], r[7]);
    *reinterpret_cast<uint4*>(hnext + (size_t)d * 64 + c16 * 4) = u;
  } else {
    float4 o0 = make_float4(r[0], r[1], r[2], r[3]);
    float4 o1 = make_float4(r[4], r[5], r[6], r[7]);
    *reinterpret_cast<float4*>(outf + (size_t)d * D + c16 * 8) = o0;
    *reinterpret_cast<float4*>(outf + (size_t)d * D + c16 * 8 + 4) = o1;
  }
}

// ---------------- launch ----------------

extern "C" void kernel_launch(void* const* d_in, const int* in_sizes, int n_in,
                              void* d_out, int out_size, void* d_ws, size_t ws_size,
                              hipStream_t stream) {
  const float* x = (const float*)d_in[0];
  const int* esrc = (const int*)d_in[1];
  const int* edst = (const int*)d_in[2];
  const float* W0 = (const float*)d_in[3];
  const float* b0 = (const float*)d_in[4];
  const float* W1 = (const float*)d_in[5];
  const float* b1 = (const float*)d_in[6];
  const float* W2 = (const float*)d_in[7];
  const float* b2 = (const float*)d_in[8];
  const float* g0 = (const float*)d_in[9];
  const float* be0 = (const float*)d_in[10];
  const float* m0 = (const float*)d_in[11];
  const float* v0 = (const float*)d_in[12];
  const float* g1 = (const float*)d_in[13];
  const float* be1 = (const float*)d_in[14];
  const float* m1 = (const float*)d_in[15];
  const float* v1 = (const float*)d_in[16];
  const int N = in_sizes[0] / D;
  const int E = in_sizes[1];

  const int SB = (E + NSL - 1) / NSL;
  const uint Msb = (uint)(((1ULL << 40) + (unsigned long long)SB - 1) / (unsigned long long)SB);

  char* p = (char*)d_ws;
  auto carve = [&](size_t bytes) {
    char* r = p;
    p += (bytes + 255) & ~(size_t)255;
    return (void*)r;
  };
  uint* hs16 = (uint*)carve((size_t)N * 64 * 4);           // GEMM out / SpMM in (f16 packed)
  ushort* Wt = (ushort*)carve((size_t)3 * D * D * 2);
  float* CA = (float*)carve((size_t)3 * D * 4);
  float* CB = (float*)carve((size_t)3 * D * 4);
  float* ns = (float*)carve((size_t)N * 4);
  float* nd = (float*)carve((size_t)N * 4);
  uint* pd = (uint*)carve((size_t)NSL * PBU * 4);
  uint* ps = (uint*)carve((size_t)NSL * PBU * 4);
  uchar* rank8 = (uchar*)carve((size_t)E);
  int* totd = (int*)carve((size_t)N * 4);
  int* rofs = (int*)carve((size_t)(N + 1) * 4);
  const int nch = (N + 1023) / 1024;
  int* csum = (int*)carve((size_t)nch * 4);
  int* csr = (int*)carve((size_t)E * 4);
  uint* bufA = (uint*)d_out;  // inter-layer f16 ping buffer lives in d_out (fully rewritten)

  k_build1<<<113, 1024, 0, stream>>>(esrc, edst, W0, W1, W2, b0, b1, b2,
                                     g0, be0, m0, v0, g1, be1, m1, v1,
                                     pd, ps, rank8, Wt, CA, CB, E, SB);
  k_build2<<<nch, 256, 0, stream>>>(pd, ps, totd, ns, nd, csum, N);
  k_scan_serial<<<1, 1, 0, stream>>>(csum, nch, rofs, N);
  k_scan_final<<<nch, 256, 0, stream>>>(totd, csum, rofs, N);
  k_scatter2<<<(E + 255) / 256, 256, 0, stream>>>(esrc, edst, rank8, pd, rofs, csr, E, Msb);

  const int gb = (N + 127) / 128;
  const int sb = (N + 15) / 16;
  // layer 0 (reads x f32 directly, ns folded in)
  k_gemm32<<<gb, 256, 0, stream>>>(x, Wt, ns, (ushort*)hs16, N);
  k_spmm16<<<sb, 256, 0, stream>>>(hs16, csr, rofs, nd, ns, CA, CB, nullptr, bufA, N, 0);
  // layer 1
  k_gemm16<<<gb, 256, 0, stream>>>((const ushort*)bufA, Wt + 16384, (ushort*)hs16, N);
  k_spmm16<<<sb, 256, 0, stream>>>(hs16, csr, rofs, nd, ns, CA + D, CB + D, nullptr, bufA, N, 0);
  // layer 2
  k_gemm16<<<gb, 256, 0, stream>>>((const ushort*)bufA, Wt + 32768, (ushort*)hs16, N);
  k_spmm16<<<sb, 256, 0, stream>>>(hs16, csr, rofs, nd, ns, CA + 2 * D, CB + 2 * D,
                                   (float*)d_out, nullptr, N, 1);
}